// Round 1
// baseline (1863.765 us; speedup 1.0000x reference)
//
#include <hip/hip_runtime.h>

// Problem constants (B=1)
constexpr int kS   = 2048;   // sequence
constexpr int kD   = 2048;   // model dim
constexpr int kH   = 32;     // heads
constexpr int kG   = 8;      // kv groups
constexpr int kHPG = 4;      // heads per group
constexpr int kHD  = 64;     // head dim
constexpr int kGHD = 512;    // kG * kHD

// ---------------------------------------------------------------------------
// GEMM: C[M,N] = A[M,K] @ B[N,K]^T + bias[N]   (torch Linear: x @ W.T + b)
// 128x128 tile, BK=16, 256 threads, 8x8 micro-tile per thread, fp32 vector.
// ---------------------------------------------------------------------------
constexpr int BM = 128, BN = 128, BK = 16;

__global__ __launch_bounds__(256) void gemm_nt_bias(
    const float* __restrict__ A, const float* __restrict__ B,
    const float* __restrict__ bias, float* __restrict__ C,
    int M, int N, int K)
{
    __shared__ float As[BK][BM + 4];   // +4 pad: keeps float4 align, breaks bank aliasing
    __shared__ float Bs[BK][BN + 4];

    const int t  = threadIdx.x;
    const int tx = t & 15;         // -> N
    const int ty = t >> 4;         // -> M
    const int m0 = blockIdx.y * BM;
    const int n0 = blockIdx.x * BN;

    const int lrow = t >> 2;            // 0..63
    const int lcol = (t & 3) << 2;      // 0,4,8,12

    const float* Aptr = A + (size_t)(m0 + lrow) * K + lcol;
    const float* Bptr = B + (size_t)(n0 + lrow) * K + lcol;

    float acc[8][8];
    #pragma unroll
    for (int i = 0; i < 8; ++i)
        #pragma unroll
        for (int j = 0; j < 8; ++j) acc[i][j] = 0.f;

    for (int k0 = 0; k0 < K; k0 += BK) {
        const float4 a0 = *(const float4*)(Aptr + k0);
        const float4 a1 = *(const float4*)(Aptr + (size_t)64 * K + k0);
        const float4 b0 = *(const float4*)(Bptr + k0);
        const float4 b1 = *(const float4*)(Bptr + (size_t)64 * K + k0);
        __syncthreads();   // previous iteration's reads complete
        As[lcol+0][lrow]    = a0.x; As[lcol+1][lrow]    = a0.y;
        As[lcol+2][lrow]    = a0.z; As[lcol+3][lrow]    = a0.w;
        As[lcol+0][lrow+64] = a1.x; As[lcol+1][lrow+64] = a1.y;
        As[lcol+2][lrow+64] = a1.z; As[lcol+3][lrow+64] = a1.w;
        Bs[lcol+0][lrow]    = b0.x; Bs[lcol+1][lrow]    = b0.y;
        Bs[lcol+2][lrow]    = b0.z; Bs[lcol+3][lrow]    = b0.w;
        Bs[lcol+0][lrow+64] = b1.x; Bs[lcol+1][lrow+64] = b1.y;
        Bs[lcol+2][lrow+64] = b1.z; Bs[lcol+3][lrow+64] = b1.w;
        __syncthreads();
        #pragma unroll
        for (int kk = 0; kk < BK; ++kk) {
            float av[8], bv[8];
            *(float4*)&av[0] = *(const float4*)&As[kk][ty * 8];
            *(float4*)&av[4] = *(const float4*)&As[kk][ty * 8 + 4];
            *(float4*)&bv[0] = *(const float4*)&Bs[kk][tx * 8];
            *(float4*)&bv[4] = *(const float4*)&Bs[kk][tx * 8 + 4];
            #pragma unroll
            for (int i = 0; i < 8; ++i)
                #pragma unroll
                for (int j = 0; j < 8; ++j)
                    acc[i][j] = fmaf(av[i], bv[j], acc[i][j]);
        }
    }

    float bvv[8];
    #pragma unroll
    for (int j = 0; j < 8; ++j) bvv[j] = bias[n0 + tx * 8 + j];

    #pragma unroll
    for (int i = 0; i < 8; ++i) {
        const int row = m0 + ty * 8 + i;
        float4 o0, o1;
        o0.x = acc[i][0] + bvv[0]; o0.y = acc[i][1] + bvv[1];
        o0.z = acc[i][2] + bvv[2]; o0.w = acc[i][3] + bvv[3];
        o1.x = acc[i][4] + bvv[4]; o1.y = acc[i][5] + bvv[5];
        o1.z = acc[i][6] + bvv[6]; o1.w = acc[i][7] + bvv[7];
        *(float4*)&C[(size_t)row * N + n0 + tx * 8]     = o0;
        *(float4*)&C[(size_t)row * N + n0 + tx * 8 + 4] = o1;
    }
}

// ---------------------------------------------------------------------------
// Flash-style GQA attention, fp32.
// grid = (S/QB, H); block = 256 (4 threads per query row).
// q: [S, D] (head h at cols h*HD), k/v: [S, GHD] (group g at cols g*HD)
// out written in reference layout: col = hp*(G*HD) + g*HD + d
// ---------------------------------------------------------------------------
constexpr int QB = 64;   // query rows per block
constexpr int KBt = 32;  // key/value rows per chunk

__global__ __launch_bounds__(256) void gqa_attn(
    const float* __restrict__ q, const float* __restrict__ k,
    const float* __restrict__ v, float* __restrict__ o)
{
    __shared__ float Qs[QB][kHD + 4];    // 17408 B
    __shared__ float Ks[KBt][kHD + 4];   //  8704 B
    __shared__ float Vs[KBt][kHD + 4];   //  8704 B
    __shared__ float Ps[QB][KBt + 1];    //  8448 B   (total ~43 KB)

    const int h   = blockIdx.y;
    const int g   = h >> 2;        // h / HPG
    const int hp  = h & 3;         // h % HPG
    const int r0  = blockIdx.x * QB;
    const int t   = threadIdx.x;
    const int r   = t >> 2;        // query row 0..63
    const int sub = t & 3;         // quarter within row
    const int kb0 = sub * 8;       // this thread's key range within chunk
    const int db0 = sub * 16;      // this thread's d range for output

    // --- load Q tile (pre-scaled by 1/sqrt(HD)) ---
    {
        const int rr = t >> 2;
        const int cc = (t & 3) * 4;
        #pragma unroll
        for (int u = 0; u < 4; ++u) {
            float4 qv = *(const float4*)&q[(size_t)(r0 + rr) * kD + h * kHD + cc + u * 16];
            qv.x *= 0.125f; qv.y *= 0.125f; qv.z *= 0.125f; qv.w *= 0.125f;
            *(float4*)&Qs[rr][cc + u * 16] = qv;
        }
    }

    float m_i = -1e30f, l_i = 0.f;
    float oacc[16];
    #pragma unroll
    for (int d = 0; d < 16; ++d) oacc[d] = 0.f;

    for (int j0 = 0; j0 < kS; j0 += KBt) {
        __syncthreads();   // previous chunk's Ks/Vs reads complete (also covers Q load, 1st iter)
        {
            const int rr = t >> 3;          // 0..31
            const int cc = (t & 7) * 4;     // 0..28
            #pragma unroll
            for (int u = 0; u < 2; ++u) {
                *(float4*)&Ks[rr][cc + u * 32] =
                    *(const float4*)&k[(size_t)(j0 + rr) * kGHD + g * kHD + cc + u * 32];
                *(float4*)&Vs[rr][cc + u * 32] =
                    *(const float4*)&v[(size_t)(j0 + rr) * kGHD + g * kHD + cc + u * 32];
            }
        }
        __syncthreads();

        // --- scores: 8 keys per thread, full 64-d dot ---
        float s[8];
        #pragma unroll
        for (int jj = 0; jj < 8; ++jj) s[jj] = 0.f;
        #pragma unroll 4
        for (int d = 0; d < kHD; d += 4) {
            const float4 qv = *(const float4*)&Qs[r][d];
            #pragma unroll
            for (int jj = 0; jj < 8; ++jj) {
                const float4 kv = *(const float4*)&Ks[kb0 + jj][d];
                float acc = s[jj];
                acc = fmaf(qv.x, kv.x, acc);
                acc = fmaf(qv.y, kv.y, acc);
                acc = fmaf(qv.z, kv.z, acc);
                acc = fmaf(qv.w, kv.w, acc);
                s[jj] = acc;
            }
        }

        // --- online softmax update (4 threads per row cooperate) ---
        float mx = s[0];
        #pragma unroll
        for (int jj = 1; jj < 8; ++jj) mx = fmaxf(mx, s[jj]);
        mx = fmaxf(mx, __shfl_xor(mx, 1));
        mx = fmaxf(mx, __shfl_xor(mx, 2));
        const float mnew = fmaxf(m_i, mx);
        const float c = __expf(m_i - mnew);
        float psum = 0.f;
        #pragma unroll
        for (int jj = 0; jj < 8; ++jj) {
            const float p = __expf(s[jj] - mnew);
            Ps[r][kb0 + jj] = p;
            psum += p;
        }
        psum += __shfl_xor(psum, 1);
        psum += __shfl_xor(psum, 2);
        l_i = l_i * c + psum;
        m_i = mnew;
        #pragma unroll
        for (int dd = 0; dd < 16; ++dd) oacc[dd] *= c;
        __syncthreads();   // Ps visible to all 4 sub-threads of each row

        // --- PV: oacc[r][db0..db0+15] += P[r][:] @ V[:][db0..] ---
        #pragma unroll 4
        for (int j = 0; j < KBt; ++j) {
            const float p = Ps[r][j];
            #pragma unroll
            for (int dd = 0; dd < 16; dd += 4) {
                const float4 vv = *(const float4*)&Vs[j][db0 + dd];
                oacc[dd+0] = fmaf(p, vv.x, oacc[dd+0]);
                oacc[dd+1] = fmaf(p, vv.y, oacc[dd+1]);
                oacc[dd+2] = fmaf(p, vv.z, oacc[dd+2]);
                oacc[dd+3] = fmaf(p, vv.w, oacc[dd+3]);
            }
        }
    }

    // --- finalize + write in reference (h g d) layout ---
    const float inv = 1.f / l_i;
    const size_t ob = (size_t)(r0 + r) * kD + hp * kGHD + g * kHD + db0;
    #pragma unroll
    for (int dd = 0; dd < 16; dd += 4) {
        float4 ov;
        ov.x = oacc[dd+0] * inv; ov.y = oacc[dd+1] * inv;
        ov.z = oacc[dd+2] * inv; ov.w = oacc[dd+3] * inv;
        *(float4*)&o[ob + dd] = ov;
    }
}

// ---------------------------------------------------------------------------
extern "C" void kernel_launch(void* const* d_in, const int* in_sizes, int n_in,
                              void* d_out, int out_size, void* d_ws, size_t ws_size,
                              hipStream_t stream)
{
    const float* x  = (const float*)d_in[0];
    const float* Wq = (const float*)d_in[1];
    const float* bq = (const float*)d_in[2];
    const float* Wk = (const float*)d_in[3];
    const float* bk = (const float*)d_in[4];
    const float* Wv = (const float*)d_in[5];
    const float* bv = (const float*)d_in[6];
    const float* Wo = (const float*)d_in[7];
    const float* bo = (const float*)d_in[8];
    float* out = (float*)d_out;

    // workspace: q | k | v | attn_out  (40 MB total, fully overwritten each call)
    float* qb = (float*)d_ws;
    float* kb = qb + (size_t)kS * kD;
    float* vb = kb + (size_t)kS * kGHD;
    float* ab = vb + (size_t)kS * kGHD;

    // projections
    gemm_nt_bias<<<dim3(kD / BN,   kS / BM), 256, 0, stream>>>(x, Wq, bq, qb, kS, kD,   kD);
    gemm_nt_bias<<<dim3(kGHD / BN, kS / BM), 256, 0, stream>>>(x, Wk, bk, kb, kS, kGHD, kD);
    gemm_nt_bias<<<dim3(kGHD / BN, kS / BM), 256, 0, stream>>>(x, Wv, bv, vb, kS, kGHD, kD);

    // attention (output already in (h g d) rearranged layout)
    gqa_attn<<<dim3(kS / QB, kH), 256, 0, stream>>>(qb, kb, vb, ab);

    // output projection
    gemm_nt_bias<<<dim3(kD / BN, kS / BM), 256, 0, stream>>>(ab, Wo, bo, out, kS, kD, kD);
}

// Round 2
// 1023.022 us; speedup vs baseline: 1.8218x; 1.8218x over previous
//
#include <hip/hip_runtime.h>
#include <hip/hip_bf16.h>

// Problem constants (B=1)
constexpr int kS   = 2048;
constexpr int kD   = 2048;
constexpr int kH   = 32;
constexpr int kG   = 8;
constexpr int kHPG = 4;
constexpr int kHD  = 64;
constexpr int kGHD = 512;
constexpr int kNQKV = kD + 2 * kGHD;   // 3072 fused QKV output cols

typedef __attribute__((ext_vector_type(8))) short bf16x8;
typedef __attribute__((ext_vector_type(4))) float f32x4;

__device__ __forceinline__ ushort f2bf(float x) {
    __hip_bfloat16 h = __float2bfloat16(x);
    return __builtin_bit_cast(ushort, h);
}
__device__ __forceinline__ float bf2f(ushort u) {
    __hip_bfloat16 h = __builtin_bit_cast(__hip_bfloat16, u);
    return __bfloat162float(h);
}

// ---------------------------------------------------------------------------
// fp32 -> bf16 (hi) + bf16 (residual lo). hi+lo carries ~16 mantissa bits.
// ---------------------------------------------------------------------------
__global__ __launch_bounds__(256) void cvt_split(
    const float* __restrict__ in, ushort* __restrict__ hi,
    ushort* __restrict__ lo, int n)
{
    const int i = (blockIdx.x * 256 + threadIdx.x) * 4;
    if (i >= n) return;
    const float4 x = *(const float4*)&in[i];
    ushort4 h, l;
    h.x = f2bf(x.x); l.x = f2bf(x.x - bf2f(h.x));
    h.y = f2bf(x.y); l.y = f2bf(x.y - bf2f(h.y));
    h.z = f2bf(x.z); l.z = f2bf(x.z - bf2f(h.z));
    h.w = f2bf(x.w); l.w = f2bf(x.w - bf2f(h.w));
    *(ushort4*)&hi[i] = h;
    *(ushort4*)&lo[i] = l;
}

// ---------------------------------------------------------------------------
// Split-bf16 MFMA GEMM:  C[M,N] = (Ah+Al)[M,K] @ (Bh+Bl)[N,K]^T + bias
//   ~fp32 accuracy via 3 products: AhBh + AhBl + AlBh.
// m97 structure: 128x128 tile, BK=32, 4 waves (2x2), 16x16x32 bf16 MFMA,
// global_load_lds width 16, 2 barriers per K-step.
// Output cols split across up to 3 destination buffers (fused QKV).
// ---------------------------------------------------------------------------
__global__ __launch_bounds__(256) void gemm_bt_split(
    const ushort* __restrict__ Ah, const ushort* __restrict__ Al,
    const ushort* __restrict__ Bh, const ushort* __restrict__ Bl,
    const float* __restrict__ bias,
    float* __restrict__ Cq, float* __restrict__ Ck, float* __restrict__ Cv,
    int K, int Nq, int Nk)
{
    __shared__ ushort lds[4][128 * 32];   // Ah | Al | Bh | Bl tiles, 32 KiB

    const int m0   = blockIdx.y * 128;
    const int n0   = blockIdx.x * 128;
    const int tid  = threadIdx.x;
    const int wid  = tid >> 6;         // wave 0..3; stages tile `wid`
    const int lane = tid & 63;
    const int wm   = wid >> 1;         // wave row (0..1) -> 64 rows
    const int wn   = wid & 1;          // wave col (0..1) -> 64 cols
    const int fr   = lane & 15;
    const int kq   = lane >> 4;

    const ushort* gsrc = (wid == 0) ? Ah : (wid == 1) ? Al : (wid == 2) ? Bh : Bl;
    const int rbase = (wid < 2) ? m0 : n0;
    const size_t grow = (size_t)(rbase + (lane >> 2));   // global row for this lane
    const int    gofs = (lane & 3) * 8;                  // ushort offset within row

    f32x4 acc[4][4];
    #pragma unroll
    for (int mi = 0; mi < 4; ++mi)
        #pragma unroll
        for (int ni = 0; ni < 4; ++ni) {
            f32x4 z = {0.f, 0.f, 0.f, 0.f};
            acc[mi][ni] = z;
        }

    for (int k0 = 0; k0 < K; k0 += 32) {
        __syncthreads();    // prior ds_reads complete before overwrite
        const ushort* gp = gsrc + grow * K + k0 + gofs;
        #pragma unroll
        for (int i = 0; i < 8; ++i) {
            __builtin_amdgcn_global_load_lds(
                (const __attribute__((address_space(1))) void*)(gp + (size_t)i * 16 * K),
                (__attribute__((address_space(3))) void*)&lds[wid][i * 512],
                16, 0, 0);
        }
        __syncthreads();    // compiler drains vmcnt(0) before barrier

        bf16x8 ah[4], al[4], bh[4], bl[4];
        #pragma unroll
        for (int f = 0; f < 4; ++f) {
            ah[f] = *(const bf16x8*)&lds[0][(wm * 64 + f * 16 + fr) * 32 + kq * 8];
            al[f] = *(const bf16x8*)&lds[1][(wm * 64 + f * 16 + fr) * 32 + kq * 8];
            bh[f] = *(const bf16x8*)&lds[2][(wn * 64 + f * 16 + fr) * 32 + kq * 8];
            bl[f] = *(const bf16x8*)&lds[3][(wn * 64 + f * 16 + fr) * 32 + kq * 8];
        }
        #pragma unroll
        for (int mi = 0; mi < 4; ++mi)
            #pragma unroll
            for (int ni = 0; ni < 4; ++ni) {
                acc[mi][ni] = __builtin_amdgcn_mfma_f32_16x16x32_bf16(ah[mi], bh[ni], acc[mi][ni], 0, 0, 0);
                acc[mi][ni] = __builtin_amdgcn_mfma_f32_16x16x32_bf16(ah[mi], bl[ni], acc[mi][ni], 0, 0, 0);
                acc[mi][ni] = __builtin_amdgcn_mfma_f32_16x16x32_bf16(al[mi], bh[ni], acc[mi][ni], 0, 0, 0);
            }
    }

    // epilogue: pick destination segment (fused QKV); C/D layout per guide §3
    float* C; int ldc, c0;
    if (n0 < Nq)            { C = Cq; ldc = Nq; c0 = n0; }
    else if (n0 < Nq + Nk)  { C = Ck; ldc = Nk; c0 = n0 - Nq; }
    else                    { C = Cv; ldc = Nk; c0 = n0 - Nq - Nk; }

    #pragma unroll
    for (int ni = 0; ni < 4; ++ni) {
        const int ncol = wn * 64 + ni * 16 + fr;
        const float bv = bias[n0 + ncol];
        #pragma unroll
        for (int mi = 0; mi < 4; ++mi) {
            #pragma unroll
            for (int i = 0; i < 4; ++i) {
                const int row = m0 + wm * 64 + mi * 16 + kq * 4 + i;
                C[(size_t)row * ldc + c0 + ncol] = acc[mi][ni][i] + bv;
            }
        }
    }
}

// ---------------------------------------------------------------------------
// Flash-style GQA attention, fp32 compute (MFMA rewrite planned next).
// Changes vs R1: key assignment j = sub + 4*jj (kills the 4-way Ks bank
// conflict: bank starts now 0/4/8/12), Ps stride 36 (conflict-free writes),
// epilogue emits bf16 hi/lo directly for the MFMA O-projection.
// ---------------------------------------------------------------------------
constexpr int QB  = 64;
constexpr int KBt = 32;

__global__ __launch_bounds__(256) void gqa_attn(
    const float* __restrict__ q, const float* __restrict__ k,
    const float* __restrict__ v, ushort* __restrict__ oh,
    ushort* __restrict__ ol)
{
    __shared__ float Qs[QB][kHD + 4];
    __shared__ float Ks[KBt][kHD + 4];
    __shared__ float Vs[KBt][kHD + 4];
    __shared__ float Ps[QB][36];

    const int h   = blockIdx.y;
    const int g   = h >> 2;
    const int hp  = h & 3;
    const int r0  = blockIdx.x * QB;
    const int t   = threadIdx.x;
    const int r   = t >> 2;
    const int sub = t & 3;
    const int db0 = sub * 16;

    {
        const int rr = t >> 2;
        const int cc = (t & 3) * 4;
        #pragma unroll
        for (int u = 0; u < 4; ++u) {
            float4 qv = *(const float4*)&q[(size_t)(r0 + rr) * kD + h * kHD + cc + u * 16];
            qv.x *= 0.125f; qv.y *= 0.125f; qv.z *= 0.125f; qv.w *= 0.125f;
            *(float4*)&Qs[rr][cc + u * 16] = qv;
        }
    }

    float m_i = -1e30f, l_i = 0.f;
    float oacc[16];
    #pragma unroll
    for (int d = 0; d < 16; ++d) oacc[d] = 0.f;

    for (int j0 = 0; j0 < kS; j0 += KBt) {
        __syncthreads();
        {
            const int rr = t >> 3;
            const int cc = (t & 7) * 4;
            #pragma unroll
            for (int u = 0; u < 2; ++u) {
                *(float4*)&Ks[rr][cc + u * 32] =
                    *(const float4*)&k[(size_t)(j0 + rr) * kGHD + g * kHD + cc + u * 32];
                *(float4*)&Vs[rr][cc + u * 32] =
                    *(const float4*)&v[(size_t)(j0 + rr) * kGHD + g * kHD + cc + u * 32];
            }
        }
        __syncthreads();

        // scores: keys j = sub + 4*jj  (conflict-free Ks reads)
        float s[8];
        #pragma unroll
        for (int jj = 0; jj < 8; ++jj) s[jj] = 0.f;
        #pragma unroll 4
        for (int d = 0; d < kHD; d += 4) {
            const float4 qv = *(const float4*)&Qs[r][d];
            #pragma unroll
            for (int jj = 0; jj < 8; ++jj) {
                const float4 kv = *(const float4*)&Ks[sub + jj * 4][d];
                float acc = s[jj];
                acc = fmaf(qv.x, kv.x, acc);
                acc = fmaf(qv.y, kv.y, acc);
                acc = fmaf(qv.z, kv.z, acc);
                acc = fmaf(qv.w, kv.w, acc);
                s[jj] = acc;
            }
        }

        float mx = s[0];
        #pragma unroll
        for (int jj = 1; jj < 8; ++jj) mx = fmaxf(mx, s[jj]);
        mx = fmaxf(mx, __shfl_xor(mx, 1));
        mx = fmaxf(mx, __shfl_xor(mx, 2));
        const float mnew = fmaxf(m_i, mx);
        const float c = __expf(m_i - mnew);
        float psum = 0.f;
        #pragma unroll
        for (int jj = 0; jj < 8; ++jj) {
            const float p = __expf(s[jj] - mnew);
            Ps[r][sub + jj * 4] = p;
            psum += p;
        }
        psum += __shfl_xor(psum, 1);
        psum += __shfl_xor(psum, 2);
        l_i = l_i * c + psum;
        m_i = mnew;
        #pragma unroll
        for (int dd = 0; dd < 16; ++dd) oacc[dd] *= c;
        __syncthreads();

        #pragma unroll 4
        for (int j = 0; j < KBt; ++j) {
            const float p = Ps[r][j];
            #pragma unroll
            for (int dd = 0; dd < 16; dd += 4) {
                const float4 vv = *(const float4*)&Vs[j][db0 + dd];
                oacc[dd+0] = fmaf(p, vv.x, oacc[dd+0]);
                oacc[dd+1] = fmaf(p, vv.y, oacc[dd+1]);
                oacc[dd+2] = fmaf(p, vv.z, oacc[dd+2]);
                oacc[dd+3] = fmaf(p, vv.w, oacc[dd+3]);
            }
        }
    }

    // finalize: write bf16 hi/lo in reference (h g d) layout
    const float inv = 1.f / l_i;
    const size_t ob = (size_t)(r0 + r) * kD + hp * kGHD + g * kHD + db0;
    #pragma unroll
    for (int dd = 0; dd < 16; dd += 4) {
        ushort4 hv, lv;
        float o0 = oacc[dd+0] * inv, o1 = oacc[dd+1] * inv;
        float o2 = oacc[dd+2] * inv, o3 = oacc[dd+3] * inv;
        hv.x = f2bf(o0); lv.x = f2bf(o0 - bf2f(hv.x));
        hv.y = f2bf(o1); lv.y = f2bf(o1 - bf2f(hv.y));
        hv.z = f2bf(o2); lv.z = f2bf(o2 - bf2f(hv.z));
        hv.w = f2bf(o3); lv.w = f2bf(o3 - bf2f(hv.w));
        *(ushort4*)&oh[ob + dd] = hv;
        *(ushort4*)&ol[ob + dd] = lv;
    }
}

// ---------------------------------------------------------------------------
extern "C" void kernel_launch(void* const* d_in, const int* in_sizes, int n_in,
                              void* d_out, int out_size, void* d_ws, size_t ws_size,
                              hipStream_t stream)
{
    const float* x  = (const float*)d_in[0];
    const float* Wq = (const float*)d_in[1];
    const float* bq = (const float*)d_in[2];
    const float* Wk = (const float*)d_in[3];
    const float* bk = (const float*)d_in[4];
    const float* Wv = (const float*)d_in[5];
    const float* bv = (const float*)d_in[6];
    const float* Wo = (const float*)d_in[7];
    const float* bo = (const float*)d_in[8];
    float* out = (float*)d_out;

    // workspace layout (~96 MB)
    char* p = (char*)d_ws;
    ushort* xh    = (ushort*)p; p += (size_t)kS * kD * 2;        // 8 MB
    ushort* xl    = (ushort*)p; p += (size_t)kS * kD * 2;        // 8 MB
    ushort* wqkvh = (ushort*)p; p += (size_t)kNQKV * kD * 2;     // 12 MB
    ushort* wqkvl = (ushort*)p; p += (size_t)kNQKV * kD * 2;     // 12 MB
    ushort* woh   = (ushort*)p; p += (size_t)kD * kD * 2;        // 8 MB
    ushort* wol   = (ushort*)p; p += (size_t)kD * kD * 2;        // 8 MB
    float*  bqkv  = (float*)p;  p += (size_t)kNQKV * 4;          // 12 KB
    float*  qb    = (float*)p;  p += (size_t)kS * kD * 4;        // 16 MB
    float*  kb2   = (float*)p;  p += (size_t)kS * kGHD * 4;      // 4 MB
    float*  vb    = (float*)p;  p += (size_t)kS * kGHD * 4;      // 4 MB
    ushort* aoh   = (ushort*)p; p += (size_t)kS * kD * 2;        // 8 MB
    ushort* aol   = (ushort*)p;                                  // 8 MB

    // fp32 -> bf16 hi/lo conversions (weights fused into QKV buffer)
    cvt_split<<<kS * kD / 1024, 256, 0, stream>>>(x, xh, xl, kS * kD);
    cvt_split<<<kD * kD / 1024, 256, 0, stream>>>(Wq, wqkvh, wqkvl, kD * kD);
    cvt_split<<<kGHD * kD / 1024, 256, 0, stream>>>(
        Wk, wqkvh + (size_t)kD * kD, wqkvl + (size_t)kD * kD, kGHD * kD);
    cvt_split<<<kGHD * kD / 1024, 256, 0, stream>>>(
        Wv, wqkvh + (size_t)(kD + kGHD) * kD, wqkvl + (size_t)(kD + kGHD) * kD, kGHD * kD);
    cvt_split<<<kD * kD / 1024, 256, 0, stream>>>(Wo, woh, wol, kD * kD);

    hipMemcpyAsync(bqkv,            bq, kD   * 4, hipMemcpyDeviceToDevice, stream);
    hipMemcpyAsync(bqkv + kD,       bk, kGHD * 4, hipMemcpyDeviceToDevice, stream);
    hipMemcpyAsync(bqkv + kD + kGHD, bv, kGHD * 4, hipMemcpyDeviceToDevice, stream);

    // fused QKV projection (MFMA), outputs fp32 q/k/v
    gemm_bt_split<<<dim3(kNQKV / 128, kS / 128), 256, 0, stream>>>(
        xh, xl, wqkvh, wqkvl, bqkv, qb, kb2, vb, kD, kD, kGHD);

    // attention (fp32 compute, bf16 hi/lo output in (h g d) layout)
    gqa_attn<<<dim3(kS / QB, kH), 256, 0, stream>>>(qb, kb2, vb, aoh, aol);

    // output projection (MFMA)
    gemm_bt_split<<<dim3(kD / 128, kS / 128), 256, 0, stream>>>(
        aoh, aol, woh, wol, bo, out, nullptr, nullptr, kD, kD, 0);
}

// Round 3
// 408.287 us; speedup vs baseline: 4.5648x; 2.5056x over previous
//
#include <hip/hip_runtime.h>
#include <hip/hip_bf16.h>

// Problem constants (B=1)
constexpr int kS   = 2048;
constexpr int kD   = 2048;
constexpr int kG   = 8;
constexpr int kHD  = 64;
constexpr int kGHD = 512;
constexpr int kNQKV = kD + 2 * kGHD;   // 3072 fused QKV output cols

typedef __attribute__((ext_vector_type(8))) short bf16x8;
typedef __attribute__((ext_vector_type(4))) float f32x4;

__device__ __forceinline__ ushort f2bf(float x) {
    __hip_bfloat16 h = __float2bfloat16(x);
    return __builtin_bit_cast(ushort, h);
}
__device__ __forceinline__ float bf2f(ushort u) {
    __hip_bfloat16 h = __builtin_bit_cast(__hip_bfloat16, u);
    return __bfloat162float(h);
}

// ---------------------------------------------------------------------------
// fp32 -> bf16 hi + bf16 residual lo
// ---------------------------------------------------------------------------
__global__ __launch_bounds__(256) void cvt_split(
    const float* __restrict__ in, ushort* __restrict__ hi,
    ushort* __restrict__ lo, int n)
{
    const int i = (blockIdx.x * 256 + threadIdx.x) * 4;
    if (i >= n) return;
    const float4 x = *(const float4*)&in[i];
    ushort4 h, l;
    h.x = f2bf(x.x); l.x = f2bf(x.x - bf2f(h.x));
    h.y = f2bf(x.y); l.y = f2bf(x.y - bf2f(h.y));
    h.z = f2bf(x.z); l.z = f2bf(x.z - bf2f(h.z));
    h.w = f2bf(x.w); l.w = f2bf(x.w - bf2f(h.w));
    *(ushort4*)&hi[i] = h;
    *(ushort4*)&lo[i] = l;
}

// ---------------------------------------------------------------------------
// Split-bf16 MFMA GEMM for QKV: C = (Ah+Al)(Bh+Bl)^T + bias, outputs bf16.
// q -> [S][D] row-major, k -> [S][GHD] row-major, v -> TRANSPOSED [GHD][S].
// ---------------------------------------------------------------------------
__global__ __launch_bounds__(256) void gemm_qkv(
    const ushort* __restrict__ Ah, const ushort* __restrict__ Al,
    const ushort* __restrict__ Bh, const ushort* __restrict__ Bl,
    const float* __restrict__ bias,
    ushort* __restrict__ qb16, ushort* __restrict__ kb16, ushort* __restrict__ vt16,
    int K)
{
    __shared__ ushort lds[4][128 * 32];

    const int m0   = blockIdx.y * 128;
    const int n0   = blockIdx.x * 128;
    const int tid  = threadIdx.x;
    const int wid  = tid >> 6;
    const int lane = tid & 63;
    const int wm   = wid >> 1;
    const int wn   = wid & 1;
    const int fr   = lane & 15;
    const int kq   = lane >> 4;

    const ushort* gsrc = (wid == 0) ? Ah : (wid == 1) ? Al : (wid == 2) ? Bh : Bl;
    const int rbase = (wid < 2) ? m0 : n0;
    const size_t grow = (size_t)(rbase + (lane >> 2));
    const int    gofs = (lane & 3) * 8;

    f32x4 acc[4][4];
    #pragma unroll
    for (int mi = 0; mi < 4; ++mi)
        #pragma unroll
        for (int ni = 0; ni < 4; ++ni) {
            f32x4 z = {0.f, 0.f, 0.f, 0.f};
            acc[mi][ni] = z;
        }

    for (int k0 = 0; k0 < K; k0 += 32) {
        __syncthreads();
        const ushort* gp = gsrc + grow * K + k0 + gofs;
        #pragma unroll
        for (int i = 0; i < 8; ++i) {
            __builtin_amdgcn_global_load_lds(
                (const __attribute__((address_space(1))) void*)(gp + (size_t)i * 16 * K),
                (__attribute__((address_space(3))) void*)&lds[wid][i * 512],
                16, 0, 0);
        }
        __syncthreads();

        bf16x8 ah[4], al[4], bh[4], bl[4];
        #pragma unroll
        for (int f = 0; f < 4; ++f) {
            ah[f] = *(const bf16x8*)&lds[0][(wm * 64 + f * 16 + fr) * 32 + kq * 8];
            al[f] = *(const bf16x8*)&lds[1][(wm * 64 + f * 16 + fr) * 32 + kq * 8];
            bh[f] = *(const bf16x8*)&lds[2][(wn * 64 + f * 16 + fr) * 32 + kq * 8];
            bl[f] = *(const bf16x8*)&lds[3][(wn * 64 + f * 16 + fr) * 32 + kq * 8];
        }
        #pragma unroll
        for (int mi = 0; mi < 4; ++mi)
            #pragma unroll
            for (int ni = 0; ni < 4; ++ni) {
                acc[mi][ni] = __builtin_amdgcn_mfma_f32_16x16x32_bf16(ah[mi], bh[ni], acc[mi][ni], 0, 0, 0);
                acc[mi][ni] = __builtin_amdgcn_mfma_f32_16x16x32_bf16(ah[mi], bl[ni], acc[mi][ni], 0, 0, 0);
                acc[mi][ni] = __builtin_amdgcn_mfma_f32_16x16x32_bf16(al[mi], bh[ni], acc[mi][ni], 0, 0, 0);
            }
    }

    const int seg = (n0 < kD) ? 0 : (n0 < kD + kGHD) ? 1 : 2;   // uniform per block
    #pragma unroll
    for (int ni = 0; ni < 4; ++ni) {
        const int ncol = n0 + wn * 64 + ni * 16 + fr;
        const float bv = bias[ncol];
        #pragma unroll
        for (int mi = 0; mi < 4; ++mi) {
            #pragma unroll
            for (int i = 0; i < 4; ++i) {
                const int row = m0 + wm * 64 + mi * 16 + kq * 4 + i;
                const ushort u = f2bf(acc[mi][ni][i] + bv);
                if (seg == 0)      qb16[(size_t)row * kD   + ncol]              = u;
                else if (seg == 1) kb16[(size_t)row * kGHD + (ncol - kD)]       = u;
                else               vt16[(size_t)(ncol - kD - kGHD) * kS + row]  = u;
            }
        }
    }
}

// ---------------------------------------------------------------------------
// Split-bf16 MFMA GEMM for O-proj: out(fp32) = (Ah+Al)(Bh+Bl)^T + bias
// ---------------------------------------------------------------------------
__global__ __launch_bounds__(256) void gemm_o(
    const ushort* __restrict__ Ah, const ushort* __restrict__ Al,
    const ushort* __restrict__ Bh, const ushort* __restrict__ Bl,
    const float* __restrict__ bias, float* __restrict__ C, int K, int N)
{
    __shared__ ushort lds[4][128 * 32];

    const int m0   = blockIdx.y * 128;
    const int n0   = blockIdx.x * 128;
    const int tid  = threadIdx.x;
    const int wid  = tid >> 6;
    const int lane = tid & 63;
    const int wm   = wid >> 1;
    const int wn   = wid & 1;
    const int fr   = lane & 15;
    const int kq   = lane >> 4;

    const ushort* gsrc = (wid == 0) ? Ah : (wid == 1) ? Al : (wid == 2) ? Bh : Bl;
    const int rbase = (wid < 2) ? m0 : n0;
    const size_t grow = (size_t)(rbase + (lane >> 2));
    const int    gofs = (lane & 3) * 8;

    f32x4 acc[4][4];
    #pragma unroll
    for (int mi = 0; mi < 4; ++mi)
        #pragma unroll
        for (int ni = 0; ni < 4; ++ni) {
            f32x4 z = {0.f, 0.f, 0.f, 0.f};
            acc[mi][ni] = z;
        }

    for (int k0 = 0; k0 < K; k0 += 32) {
        __syncthreads();
        const ushort* gp = gsrc + grow * K + k0 + gofs;
        #pragma unroll
        for (int i = 0; i < 8; ++i) {
            __builtin_amdgcn_global_load_lds(
                (const __attribute__((address_space(1))) void*)(gp + (size_t)i * 16 * K),
                (__attribute__((address_space(3))) void*)&lds[wid][i * 512],
                16, 0, 0);
        }
        __syncthreads();

        bf16x8 ah[4], al[4], bh[4], bl[4];
        #pragma unroll
        for (int f = 0; f < 4; ++f) {
            ah[f] = *(const bf16x8*)&lds[0][(wm * 64 + f * 16 + fr) * 32 + kq * 8];
            al[f] = *(const bf16x8*)&lds[1][(wm * 64 + f * 16 + fr) * 32 + kq * 8];
            bh[f] = *(const bf16x8*)&lds[2][(wn * 64 + f * 16 + fr) * 32 + kq * 8];
            bl[f] = *(const bf16x8*)&lds[3][(wn * 64 + f * 16 + fr) * 32 + kq * 8];
        }
        #pragma unroll
        for (int mi = 0; mi < 4; ++mi)
            #pragma unroll
            for (int ni = 0; ni < 4; ++ni) {
                acc[mi][ni] = __builtin_amdgcn_mfma_f32_16x16x32_bf16(ah[mi], bh[ni], acc[mi][ni], 0, 0, 0);
                acc[mi][ni] = __builtin_amdgcn_mfma_f32_16x16x32_bf16(ah[mi], bl[ni], acc[mi][ni], 0, 0, 0);
                acc[mi][ni] = __builtin_amdgcn_mfma_f32_16x16x32_bf16(al[mi], bh[ni], acc[mi][ni], 0, 0, 0);
            }
    }

    #pragma unroll
    for (int ni = 0; ni < 4; ++ni) {
        const int ncol = wn * 64 + ni * 16 + fr;
        const float bv = bias[n0 + ncol];
        #pragma unroll
        for (int mi = 0; mi < 4; ++mi)
            #pragma unroll
            for (int i = 0; i < 4; ++i) {
                const int row = m0 + wm * 64 + mi * 16 + kq * 4 + i;
                C[(size_t)row * N + n0 + ncol] = acc[mi][ni][i] + bv;
            }
    }
}

// ---------------------------------------------------------------------------
// MFMA flash attention, pure bf16 operands, fp32 accum.
// grid = (S/64, G); block = 256 = 4 waves = 4 heads of group g.
// Per kv-tile(64): stage K[64][64] + V^T[64][64] bf16 in LDS (XOR-swizzled
// via pre-swizzled global_load_lds source); QK^T MFMA -> online softmax in
// registers -> P via swizzled LDS roundtrip -> PV MFMA.
// Output: bf16 hi/lo in reference (hp g d) column layout.
// ---------------------------------------------------------------------------
__global__ __launch_bounds__(256) void gqa_attn_mfma(
    const ushort* __restrict__ qb,   // [S][D] bf16
    const ushort* __restrict__ kb,   // [S][GHD] bf16
    const ushort* __restrict__ vt,   // [GHD][S] bf16 (V transposed)
    ushort* __restrict__ oh, ushort* __restrict__ ol)
{
    __shared__ ushort Kt[64 * 64];      // swizzled [k-row][d]
    __shared__ ushort Vt[64 * 64];      // swizzled [d][k-col]
    __shared__ ushort Pt[4][64 * 64];   // per-wave swizzled [q][k]

    const int g    = blockIdx.y;
    const int q0   = blockIdx.x * 64;
    const int tid  = threadIdx.x;
    const int w    = tid >> 6;          // wave = head-in-group (hp)
    const int lane = tid & 63;
    const int fr   = lane & 15;
    const int lq   = lane >> 4;
    const int h    = g * 4 + w;

    // --- hoist Q fragments to registers (A-operand: lane&15 = q-row) ---
    bf16x8 qf[4][2];
    #pragma unroll
    for (int mi = 0; mi < 4; ++mi)
        #pragma unroll
        for (int ks = 0; ks < 2; ++ks)
            qf[mi][ks] = *(const bf16x8*)&qb[(size_t)(q0 + mi * 16 + fr) * kD
                                             + h * kHD + ks * 32 + lq * 8];

    float mrow[4][4], lrow[4][4];
    #pragma unroll
    for (int mi = 0; mi < 4; ++mi)
        #pragma unroll
        for (int i = 0; i < 4; ++i) { mrow[mi][i] = -1e30f; lrow[mi][i] = 0.f; }

    f32x4 oacc[4][4];
    #pragma unroll
    for (int mi = 0; mi < 4; ++mi)
        #pragma unroll
        for (int ni = 0; ni < 4; ++ni) {
            f32x4 z = {0.f, 0.f, 0.f, 0.f};
            oacc[mi][ni] = z;
        }

    const int srow8 = lane >> 3;    // staging: row-in-issue 0..7
    const int ssl   = lane & 7;     // staging: lds 16B-slot

    for (int t = 0; t < kS; t += 64) {
        __syncthreads();   // all waves done reading previous K/V tiles
        // --- stage K and V^T (each wave: 16 rows of each, 2 issues) ---
        #pragma unroll
        for (int j = 0; j < 2; ++j) {
            const int r = w * 16 + j * 8 + srow8;          // tile row
            const int s = ssl ^ (r & 7);                   // pre-swizzled source slot
            __builtin_amdgcn_global_load_lds(
                (const __attribute__((address_space(1))) void*)
                    (kb + (size_t)(t + r) * kGHD + g * kHD + s * 8),
                (__attribute__((address_space(3))) void*)(Kt + (w * 16 + j * 8) * 64),
                16, 0, 0);
            __builtin_amdgcn_global_load_lds(
                (const __attribute__((address_space(1))) void*)
                    (vt + (size_t)(g * kHD + r) * kS + t + s * 8),
                (__attribute__((address_space(3))) void*)(Vt + (w * 16 + j * 8) * 64),
                16, 0, 0);
        }
        __syncthreads();   // staging complete (compiler drains vmcnt before barrier)

        // --- QK^T: S[64q x 64k], raw scores ---
        f32x4 s[4][4];
        #pragma unroll
        for (int mi = 0; mi < 4; ++mi)
            #pragma unroll
            for (int ni = 0; ni < 4; ++ni) {
                f32x4 z = {0.f, 0.f, 0.f, 0.f};
                s[mi][ni] = z;
            }
        #pragma unroll
        for (int ks = 0; ks < 2; ++ks) {
            bf16x8 kf[4];
            #pragma unroll
            for (int ni = 0; ni < 4; ++ni)
                kf[ni] = *(const bf16x8*)&Kt[(ni * 16 + fr) * 64
                                             + (((ks * 4 + lq) ^ (fr & 7)) * 8)];
            #pragma unroll
            for (int mi = 0; mi < 4; ++mi)
                #pragma unroll
                for (int ni = 0; ni < 4; ++ni)
                    s[mi][ni] = __builtin_amdgcn_mfma_f32_16x16x32_bf16(
                        qf[mi][ks], kf[ni], s[mi][ni], 0, 0, 0);
        }

        // --- online softmax (scale 1/8 folded into exp args) ---
        #pragma unroll
        for (int mi = 0; mi < 4; ++mi) {
            #pragma unroll
            for (int i = 0; i < 4; ++i) {
                float mt = fmaxf(fmaxf(s[mi][0][i], s[mi][1][i]),
                                 fmaxf(s[mi][2][i], s[mi][3][i]));
                mt = fmaxf(mt, __shfl_xor(mt, 1));
                mt = fmaxf(mt, __shfl_xor(mt, 2));
                mt = fmaxf(mt, __shfl_xor(mt, 4));
                mt = fmaxf(mt, __shfl_xor(mt, 8));
                const float mnew = fmaxf(mrow[mi][i], mt);
                const float c = __expf((mrow[mi][i] - mnew) * 0.125f);
                float ps = 0.f;
                #pragma unroll
                for (int ni = 0; ni < 4; ++ni) {
                    const float p = __expf((s[mi][ni][i] - mnew) * 0.125f);
                    s[mi][ni][i] = p;
                    ps += p;
                }
                ps += __shfl_xor(ps, 1);
                ps += __shfl_xor(ps, 2);
                ps += __shfl_xor(ps, 4);
                ps += __shfl_xor(ps, 8);
                lrow[mi][i] = lrow[mi][i] * c + ps;
                mrow[mi][i] = mnew;
                #pragma unroll
                for (int ni = 0; ni < 4; ++ni)
                    oacc[mi][ni][i] *= c;
            }
        }

        // --- P -> bf16 -> swizzled LDS (same-wave buffer; lgkmcnt orders RAW) ---
        #pragma unroll
        for (int mi = 0; mi < 4; ++mi)
            #pragma unroll
            for (int i = 0; i < 4; ++i) {
                const int qr = mi * 16 + lq * 4 + i;
                #pragma unroll
                for (int ni = 0; ni < 4; ++ni) {
                    const int slot = (ni * 2 + (fr >> 3)) ^ (qr & 7);
                    Pt[w][qr * 64 + slot * 8 + (fr & 7)] = f2bf(s[mi][ni][i]);
                }
            }

        // --- PV: O += P @ V (B-operand from V^T rows) ---
        #pragma unroll
        for (int ks = 0; ks < 2; ++ks) {
            bf16x8 pf[4], vf[4];
            #pragma unroll
            for (int mi = 0; mi < 4; ++mi)
                pf[mi] = *(const bf16x8*)&Pt[w][(mi * 16 + fr) * 64
                                                + (((ks * 4 + lq) ^ (fr & 7)) * 8)];
            #pragma unroll
            for (int ni = 0; ni < 4; ++ni)
                vf[ni] = *(const bf16x8*)&Vt[(ni * 16 + fr) * 64
                                             + (((ks * 4 + lq) ^ (fr & 7)) * 8)];
            #pragma unroll
            for (int mi = 0; mi < 4; ++mi)
                #pragma unroll
                for (int ni = 0; ni < 4; ++ni)
                    oacc[mi][ni] = __builtin_amdgcn_mfma_f32_16x16x32_bf16(
                        pf[mi], vf[ni], oacc[mi][ni], 0, 0, 0);
        }
    }

    // --- finalize: O/l, split hi/lo, reference (hp g d) layout ---
    #pragma unroll
    for (int mi = 0; mi < 4; ++mi)
        #pragma unroll
        for (int i = 0; i < 4; ++i) {
            const float inv = 1.f / lrow[mi][i];
            const size_t row = q0 + mi * 16 + lq * 4 + i;
            #pragma unroll
            for (int ni = 0; ni < 4; ++ni) {
                const float o = oacc[mi][ni][i] * inv;
                const ushort hv = f2bf(o);
                const ushort lv = f2bf(o - bf2f(hv));
                const size_t addr = row * kD + w * kGHD + g * kHD + ni * 16 + fr;
                oh[addr] = hv;
                ol[addr] = lv;
            }
        }
}

// ---------------------------------------------------------------------------
extern "C" void kernel_launch(void* const* d_in, const int* in_sizes, int n_in,
                              void* d_out, int out_size, void* d_ws, size_t ws_size,
                              hipStream_t stream)
{
    const float* x  = (const float*)d_in[0];
    const float* Wq = (const float*)d_in[1];
    const float* bq = (const float*)d_in[2];
    const float* Wk = (const float*)d_in[3];
    const float* bk = (const float*)d_in[4];
    const float* Wv = (const float*)d_in[5];
    const float* bv = (const float*)d_in[6];
    const float* Wo = (const float*)d_in[7];
    const float* bo = (const float*)d_in[8];
    float* out = (float*)d_out;

    // workspace layout (~84 MB)
    char* p = (char*)d_ws;
    ushort* xh    = (ushort*)p; p += (size_t)kS * kD * 2;
    ushort* xl    = (ushort*)p; p += (size_t)kS * kD * 2;
    ushort* wqkvh = (ushort*)p; p += (size_t)kNQKV * kD * 2;
    ushort* wqkvl = (ushort*)p; p += (size_t)kNQKV * kD * 2;
    ushort* woh   = (ushort*)p; p += (size_t)kD * kD * 2;
    ushort* wol   = (ushort*)p; p += (size_t)kD * kD * 2;
    float*  bqkv  = (float*)p;  p += 16384;
    ushort* qb16  = (ushort*)p; p += (size_t)kS * kD * 2;
    ushort* kb16  = (ushort*)p; p += (size_t)kS * kGHD * 2;
    ushort* vt16  = (ushort*)p; p += (size_t)kGHD * kS * 2;
    ushort* aoh   = (ushort*)p; p += (size_t)kS * kD * 2;
    ushort* aol   = (ushort*)p;

    cvt_split<<<kS * kD / 1024, 256, 0, stream>>>(x, xh, xl, kS * kD);
    cvt_split<<<kD * kD / 1024, 256, 0, stream>>>(Wq, wqkvh, wqkvl, kD * kD);
    cvt_split<<<kGHD * kD / 1024, 256, 0, stream>>>(
        Wk, wqkvh + (size_t)kD * kD, wqkvl + (size_t)kD * kD, kGHD * kD);
    cvt_split<<<kGHD * kD / 1024, 256, 0, stream>>>(
        Wv, wqkvh + (size_t)(kD + kGHD) * kD, wqkvl + (size_t)(kD + kGHD) * kD, kGHD * kD);
    cvt_split<<<kD * kD / 1024, 256, 0, stream>>>(Wo, woh, wol, kD * kD);

    hipMemcpyAsync(bqkv,             bq, kD   * 4, hipMemcpyDeviceToDevice, stream);
    hipMemcpyAsync(bqkv + kD,        bk, kGHD * 4, hipMemcpyDeviceToDevice, stream);
    hipMemcpyAsync(bqkv + kD + kGHD, bv, kGHD * 4, hipMemcpyDeviceToDevice, stream);

    // fused QKV projection -> q,k bf16 row-major; v bf16 transposed
    gemm_qkv<<<dim3(kNQKV / 128, kS / 128), 256, 0, stream>>>(
        xh, xl, wqkvh, wqkvl, bqkv, qb16, kb16, vt16, kD);

    // MFMA flash attention
    gqa_attn_mfma<<<dim3(kS / 64, kG), 256, 0, stream>>>(qb16, kb16, vt16, aoh, aol);

    // output projection
    gemm_o<<<dim3(kD / 128, kS / 128), 256, 0, stream>>>(
        aoh, aol, woh, wol, bo, out, kD, kD);
}

// Round 4
// 274.496 us; speedup vs baseline: 6.7898x; 1.4874x over previous
//
#include <hip/hip_runtime.h>
#include <hip/hip_bf16.h>

// Problem constants (B=1)
constexpr int kS   = 2048;
constexpr int kD   = 2048;
constexpr int kG   = 8;
constexpr int kHD  = 64;
constexpr int kGHD = 512;
constexpr int kNQKV = kD + 2 * kGHD;   // 3072 fused QKV output cols

typedef __attribute__((ext_vector_type(8))) short    bf16x8;
typedef __attribute__((ext_vector_type(8))) _Float16 f16x8;
typedef __attribute__((ext_vector_type(4))) float    f32x4;

__device__ __forceinline__ ushort f2bf(float x) {
    __hip_bfloat16 h = __float2bfloat16(x);
    return __builtin_bit_cast(ushort, h);
}
__device__ __forceinline__ float bf2f(ushort u) {
    __hip_bfloat16 h = __builtin_bit_cast(__hip_bfloat16, u);
    return __bfloat162float(h);
}
__device__ __forceinline__ ushort f2h(float x) {
    return __builtin_bit_cast(ushort, (_Float16)x);
}

// ---------------------------------------------------------------------------
// fp32 -> f16 (single)
// ---------------------------------------------------------------------------
__global__ __launch_bounds__(256) void cvt_f16(
    const float* __restrict__ in, ushort* __restrict__ out, int n)
{
    const int i = (blockIdx.x * 256 + threadIdx.x) * 4;
    if (i >= n) return;
    const float4 x = *(const float4*)&in[i];
    ushort4 o;
    o.x = f2h(x.x); o.y = f2h(x.y); o.z = f2h(x.z); o.w = f2h(x.w);
    *(ushort4*)&out[i] = o;
}

// ---------------------------------------------------------------------------
// fp32 -> bf16 hi + bf16 residual lo (for O-proj operands)
// ---------------------------------------------------------------------------
__global__ __launch_bounds__(256) void cvt_split(
    const float* __restrict__ in, ushort* __restrict__ hi,
    ushort* __restrict__ lo, int n)
{
    const int i = (blockIdx.x * 256 + threadIdx.x) * 4;
    if (i >= n) return;
    const float4 x = *(const float4*)&in[i];
    ushort4 h, l;
    h.x = f2bf(x.x); l.x = f2bf(x.x - bf2f(h.x));
    h.y = f2bf(x.y); l.y = f2bf(x.y - bf2f(h.y));
    h.z = f2bf(x.z); l.z = f2bf(x.z - bf2f(h.z));
    h.w = f2bf(x.w); l.w = f2bf(x.w - bf2f(h.w));
    *(ushort4*)&hi[i] = h;
    *(ushort4*)&lo[i] = l;
}

// ---------------------------------------------------------------------------
// Single-product f16 MFMA GEMM for QKV: C = A @ B^T + bias, outputs f16.
// q -> [S][D], k -> [S][GHD], v -> TRANSPOSED [GHD][S].
// ---------------------------------------------------------------------------
__global__ __launch_bounds__(256) void gemm_qkv(
    const ushort* __restrict__ Af, const ushort* __restrict__ Bf,
    const float* __restrict__ bias,
    ushort* __restrict__ qb16, ushort* __restrict__ kb16, ushort* __restrict__ vt16,
    int K)
{
    __shared__ ushort lds[2][128 * 32];   // A | B f16 tiles

    const int m0   = blockIdx.y * 128;
    const int n0   = blockIdx.x * 128;
    const int tid  = threadIdx.x;
    const int wid  = tid >> 6;
    const int lane = tid & 63;
    const int wm   = wid >> 1;
    const int wn   = wid & 1;
    const int fr   = lane & 15;
    const int kq   = lane >> 4;

    // staging: waves 0,1 -> A rows 0-63 / 64-127; waves 2,3 -> B likewise
    const ushort* gsrc = (wid < 2) ? Af : Bf;
    const int  rbase = (wid < 2) ? m0 : n0;
    const size_t grow = (size_t)(rbase + (wid & 1) * 64 + (lane >> 2));
    const int    gofs = (lane & 3) * 8;
    const int    tsel = wid >> 1;
    const int    lofs = (wid & 1) * 2048;

    f32x4 acc[4][4];
    #pragma unroll
    for (int mi = 0; mi < 4; ++mi)
        #pragma unroll
        for (int ni = 0; ni < 4; ++ni) {
            f32x4 z = {0.f, 0.f, 0.f, 0.f};
            acc[mi][ni] = z;
        }

    for (int k0 = 0; k0 < K; k0 += 32) {
        __syncthreads();
        const ushort* gp = gsrc + grow * K + k0 + gofs;
        #pragma unroll
        for (int i = 0; i < 4; ++i) {
            __builtin_amdgcn_global_load_lds(
                (const __attribute__((address_space(1))) void*)(gp + (size_t)i * 16 * K),
                (__attribute__((address_space(3))) void*)&lds[tsel][lofs + i * 512],
                16, 0, 0);
        }
        __syncthreads();

        f16x8 af[4], bfr[4];
        #pragma unroll
        for (int f = 0; f < 4; ++f) {
            af[f]  = *(const f16x8*)&lds[0][(wm * 64 + f * 16 + fr) * 32 + kq * 8];
            bfr[f] = *(const f16x8*)&lds[1][(wn * 64 + f * 16 + fr) * 32 + kq * 8];
        }
        #pragma unroll
        for (int mi = 0; mi < 4; ++mi)
            #pragma unroll
            for (int ni = 0; ni < 4; ++ni)
                acc[mi][ni] = __builtin_amdgcn_mfma_f32_16x16x32_f16(
                    af[mi], bfr[ni], acc[mi][ni], 0, 0, 0);
    }

    const int seg = (n0 < kD) ? 0 : (n0 < kD + kGHD) ? 1 : 2;   // uniform per block
    #pragma unroll
    for (int ni = 0; ni < 4; ++ni) {
        const int ncol = n0 + wn * 64 + ni * 16 + fr;
        const float bv = bias[ncol];
        #pragma unroll
        for (int mi = 0; mi < 4; ++mi) {
            #pragma unroll
            for (int i = 0; i < 4; ++i) {
                const int row = m0 + wm * 64 + mi * 16 + kq * 4 + i;
                const ushort u = f2h(acc[mi][ni][i] + bv);
                if (seg == 0)      qb16[(size_t)row * kD   + ncol]              = u;
                else if (seg == 1) kb16[(size_t)row * kGHD + (ncol - kD)]       = u;
                else               vt16[(size_t)(ncol - kD - kGHD) * kS + row]  = u;
            }
        }
    }
}

// ---------------------------------------------------------------------------
// Split-bf16 MFMA GEMM for O-proj: out(fp32) = (Ah+Al)(Bh+Bl)^T + bias
// ---------------------------------------------------------------------------
__global__ __launch_bounds__(256) void gemm_o(
    const ushort* __restrict__ Ah, const ushort* __restrict__ Al,
    const ushort* __restrict__ Bh, const ushort* __restrict__ Bl,
    const float* __restrict__ bias, float* __restrict__ C, int K, int N)
{
    __shared__ ushort lds[4][128 * 32];

    const int m0   = blockIdx.y * 128;
    const int n0   = blockIdx.x * 128;
    const int tid  = threadIdx.x;
    const int wid  = tid >> 6;
    const int lane = tid & 63;
    const int wm   = wid >> 1;
    const int wn   = wid & 1;
    const int fr   = lane & 15;
    const int kq   = lane >> 4;

    const ushort* gsrc = (wid == 0) ? Ah : (wid == 1) ? Al : (wid == 2) ? Bh : Bl;
    const int rbase = (wid < 2) ? m0 : n0;
    const size_t grow = (size_t)(rbase + (lane >> 2));
    const int    gofs = (lane & 3) * 8;

    f32x4 acc[4][4];
    #pragma unroll
    for (int mi = 0; mi < 4; ++mi)
        #pragma unroll
        for (int ni = 0; ni < 4; ++ni) {
            f32x4 z = {0.f, 0.f, 0.f, 0.f};
            acc[mi][ni] = z;
        }

    for (int k0 = 0; k0 < K; k0 += 32) {
        __syncthreads();
        const ushort* gp = gsrc + grow * K + k0 + gofs;
        #pragma unroll
        for (int i = 0; i < 8; ++i) {
            __builtin_amdgcn_global_load_lds(
                (const __attribute__((address_space(1))) void*)(gp + (size_t)i * 16 * K),
                (__attribute__((address_space(3))) void*)&lds[wid][i * 512],
                16, 0, 0);
        }
        __syncthreads();

        bf16x8 ah[4], al[4], bh[4], bl[4];
        #pragma unroll
        for (int f = 0; f < 4; ++f) {
            ah[f] = *(const bf16x8*)&lds[0][(wm * 64 + f * 16 + fr) * 32 + kq * 8];
            al[f] = *(const bf16x8*)&lds[1][(wm * 64 + f * 16 + fr) * 32 + kq * 8];
            bh[f] = *(const bf16x8*)&lds[2][(wn * 64 + f * 16 + fr) * 32 + kq * 8];
            bl[f] = *(const bf16x8*)&lds[3][(wn * 64 + f * 16 + fr) * 32 + kq * 8];
        }
        #pragma unroll
        for (int mi = 0; mi < 4; ++mi)
            #pragma unroll
            for (int ni = 0; ni < 4; ++ni) {
                acc[mi][ni] = __builtin_amdgcn_mfma_f32_16x16x32_bf16(ah[mi], bh[ni], acc[mi][ni], 0, 0, 0);
                acc[mi][ni] = __builtin_amdgcn_mfma_f32_16x16x32_bf16(ah[mi], bl[ni], acc[mi][ni], 0, 0, 0);
                acc[mi][ni] = __builtin_amdgcn_mfma_f32_16x16x32_bf16(al[mi], bh[ni], acc[mi][ni], 0, 0, 0);
            }
    }

    #pragma unroll
    for (int ni = 0; ni < 4; ++ni) {
        const int ncol = wn * 64 + ni * 16 + fr;
        const float bv = bias[n0 + ncol];
        #pragma unroll
        for (int mi = 0; mi < 4; ++mi)
            #pragma unroll
            for (int i = 0; i < 4; ++i) {
                const int row = m0 + wm * 64 + mi * 16 + kq * 4 + i;
                C[(size_t)row * N + n0 + ncol] = acc[mi][ni][i] + bv;
            }
    }
}

// ---------------------------------------------------------------------------
// MFMA flash attention, f16 operands, fp32 accum.
// grid = (S/64, G); block = 512 = 8 waves: wave w -> head hp=w&3, q-half w>>2.
// K/V tiles (64 kv rows) double-buffered; next tile's global_load_lds issued
// before compute (drained by next __syncthreads) -> loads hide under compute.
// Output: bf16 hi/lo in reference (hp g d) column layout.
// ---------------------------------------------------------------------------
__global__ __launch_bounds__(512) void gqa_attn_mfma(
    const ushort* __restrict__ qb,   // [S][D] f16
    const ushort* __restrict__ kb,   // [S][GHD] f16
    const ushort* __restrict__ vt,   // [GHD][S] f16 (V transposed)
    ushort* __restrict__ oh, ushort* __restrict__ ol)
{
    __shared__ ushort Kt[2][64 * 64];     // swizzled [k-row][d], dbuf
    __shared__ ushort Vt[2][64 * 64];     // swizzled [d][k-col], dbuf
    __shared__ ushort Pt[8][32 * 64];     // per-wave swizzled [q][k]

    const int g    = blockIdx.y;
    const int q0   = blockIdx.x * 64;
    const int tid  = threadIdx.x;
    const int w    = tid >> 6;
    const int lane = tid & 63;
    const int hp   = w & 3;
    const int qh   = w >> 2;
    const int fr   = lane & 15;
    const int lq   = lane >> 4;
    const int h    = g * 4 + hp;
    const int qbase = q0 + qh * 32;

    // staging assignment: wave w covers tile rows w*8 .. w*8+7
    const int r = w * 8 + (lane >> 3);
    const int s = (lane & 7) ^ (r & 7);    // pre-swizzled source slot

    // prologue: stage tile 0 into buf 0
    __builtin_amdgcn_global_load_lds(
        (const __attribute__((address_space(1))) void*)(kb + (size_t)r * kGHD + g * kHD + s * 8),
        (__attribute__((address_space(3))) void*)(Kt[0] + w * 512), 16, 0, 0);
    __builtin_amdgcn_global_load_lds(
        (const __attribute__((address_space(1))) void*)(vt + (size_t)(g * kHD + r) * kS + s * 8),
        (__attribute__((address_space(3))) void*)(Vt[0] + w * 512), 16, 0, 0);

    // hoist Q fragments (A-operand: lane&15 = q-row)
    f16x8 qf[2][2];
    #pragma unroll
    for (int mi = 0; mi < 2; ++mi)
        #pragma unroll
        for (int ks = 0; ks < 2; ++ks)
            qf[mi][ks] = *(const f16x8*)&qb[(size_t)(qbase + mi * 16 + fr) * kD
                                            + h * kHD + ks * 32 + lq * 8];

    float mrow[2][4], lrow[2][4];
    #pragma unroll
    for (int mi = 0; mi < 2; ++mi)
        #pragma unroll
        for (int i = 0; i < 4; ++i) { mrow[mi][i] = -1e30f; lrow[mi][i] = 0.f; }

    f32x4 oacc[2][4];
    #pragma unroll
    for (int mi = 0; mi < 2; ++mi)
        #pragma unroll
        for (int ni = 0; ni < 4; ++ni) {
            f32x4 z = {0.f, 0.f, 0.f, 0.f};
            oacc[mi][ni] = z;
        }

    int cur = 0;
    for (int t = 0; t < kS; t += 64) {
        __syncthreads();   // drains vmcnt: buf[cur] staged; all reads of buf[cur^1] done

        // issue next tile's loads (fly under this tile's compute)
        if (t + 64 < kS) {
            __builtin_amdgcn_global_load_lds(
                (const __attribute__((address_space(1))) void*)
                    (kb + (size_t)(t + 64 + r) * kGHD + g * kHD + s * 8),
                (__attribute__((address_space(3))) void*)(Kt[cur ^ 1] + w * 512), 16, 0, 0);
            __builtin_amdgcn_global_load_lds(
                (const __attribute__((address_space(1))) void*)
                    (vt + (size_t)(g * kHD + r) * kS + t + 64 + s * 8),
                (__attribute__((address_space(3))) void*)(Vt[cur ^ 1] + w * 512), 16, 0, 0);
        }

        // --- QK^T: S[32q x 64k] per wave ---
        f32x4 sc[2][4];
        #pragma unroll
        for (int mi = 0; mi < 2; ++mi)
            #pragma unroll
            for (int ni = 0; ni < 4; ++ni) {
                f32x4 z = {0.f, 0.f, 0.f, 0.f};
                sc[mi][ni] = z;
            }
        #pragma unroll
        for (int ks = 0; ks < 2; ++ks) {
            f16x8 kf[4];
            #pragma unroll
            for (int ni = 0; ni < 4; ++ni)
                kf[ni] = *(const f16x8*)&Kt[cur][(ni * 16 + fr) * 64
                                                 + (((ks * 4 + lq) ^ (fr & 7)) * 8)];
            #pragma unroll
            for (int mi = 0; mi < 2; ++mi)
                #pragma unroll
                for (int ni = 0; ni < 4; ++ni)
                    sc[mi][ni] = __builtin_amdgcn_mfma_f32_16x16x32_f16(
                        qf[mi][ks], kf[ni], sc[mi][ni], 0, 0, 0);
        }

        // --- online softmax (scale 1/8 folded into exp args) ---
        #pragma unroll
        for (int mi = 0; mi < 2; ++mi) {
            #pragma unroll
            for (int i = 0; i < 4; ++i) {
                float mt = fmaxf(fmaxf(sc[mi][0][i], sc[mi][1][i]),
                                 fmaxf(sc[mi][2][i], sc[mi][3][i]));
                mt = fmaxf(mt, __shfl_xor(mt, 1));
                mt = fmaxf(mt, __shfl_xor(mt, 2));
                mt = fmaxf(mt, __shfl_xor(mt, 4));
                mt = fmaxf(mt, __shfl_xor(mt, 8));
                const float mnew = fmaxf(mrow[mi][i], mt);
                const float c = __expf((mrow[mi][i] - mnew) * 0.125f);
                float ps = 0.f;
                #pragma unroll
                for (int ni = 0; ni < 4; ++ni) {
                    const float p = __expf((sc[mi][ni][i] - mnew) * 0.125f);
                    sc[mi][ni][i] = p;
                    ps += p;
                }
                ps += __shfl_xor(ps, 1);
                ps += __shfl_xor(ps, 2);
                ps += __shfl_xor(ps, 4);
                ps += __shfl_xor(ps, 8);
                lrow[mi][i] = lrow[mi][i] * c + ps;
                mrow[mi][i] = mnew;
                #pragma unroll
                for (int ni = 0; ni < 4; ++ni)
                    oacc[mi][ni][i] *= c;
            }
        }

        // --- P -> f16 -> swizzled per-wave LDS (same-wave RAW, lgkmcnt orders) ---
        #pragma unroll
        for (int mi = 0; mi < 2; ++mi)
            #pragma unroll
            for (int i = 0; i < 4; ++i) {
                const int qr = mi * 16 + lq * 4 + i;
                #pragma unroll
                for (int ni = 0; ni < 4; ++ni) {
                    const int slot = (ni * 2 + (fr >> 3)) ^ (qr & 7);
                    Pt[w][qr * 64 + slot * 8 + (fr & 7)] = f2h(sc[mi][ni][i]);
                }
            }

        // --- PV: O += P @ V ---
        #pragma unroll
        for (int ks = 0; ks < 2; ++ks) {
            f16x8 pf[2], vf[4];
            #pragma unroll
            for (int mi = 0; mi < 2; ++mi)
                pf[mi] = *(const f16x8*)&Pt[w][(mi * 16 + fr) * 64
                                               + (((ks * 4 + lq) ^ (fr & 7)) * 8)];
            #pragma unroll
            for (int ni = 0; ni < 4; ++ni)
                vf[ni] = *(const f16x8*)&Vt[cur][(ni * 16 + fr) * 64
                                                 + (((ks * 4 + lq) ^ (fr & 7)) * 8)];
            #pragma unroll
            for (int mi = 0; mi < 2; ++mi)
                #pragma unroll
                for (int ni = 0; ni < 4; ++ni)
                    oacc[mi][ni] = __builtin_amdgcn_mfma_f32_16x16x32_f16(
                        pf[mi], vf[ni], oacc[mi][ni], 0, 0, 0);
        }
        cur ^= 1;
    }

    // --- finalize: O/l, split bf16 hi/lo, reference (hp g d) layout ---
    #pragma unroll
    for (int mi = 0; mi < 2; ++mi)
        #pragma unroll
        for (int i = 0; i < 4; ++i) {
            const float inv = 1.f / lrow[mi][i];
            const size_t row = qbase + mi * 16 + lq * 4 + i;
            #pragma unroll
            for (int ni = 0; ni < 4; ++ni) {
                const float o = oacc[mi][ni][i] * inv;
                const ushort hv = f2bf(o);
                const ushort lv = f2bf(o - bf2f(hv));
                const size_t addr = row * kD + hp * kGHD + g * kHD + ni * 16 + fr;
                oh[addr] = hv;
                ol[addr] = lv;
            }
        }
}

// ---------------------------------------------------------------------------
extern "C" void kernel_launch(void* const* d_in, const int* in_sizes, int n_in,
                              void* d_out, int out_size, void* d_ws, size_t ws_size,
                              hipStream_t stream)
{
    const float* x  = (const float*)d_in[0];
    const float* Wq = (const float*)d_in[1];
    const float* bq = (const float*)d_in[2];
    const float* Wk = (const float*)d_in[3];
    const float* bk = (const float*)d_in[4];
    const float* Wv = (const float*)d_in[5];
    const float* bv = (const float*)d_in[6];
    const float* Wo = (const float*)d_in[7];
    const float* bo = (const float*)d_in[8];
    float* out = (float*)d_out;

    // workspace layout (~64 MB)
    char* p = (char*)d_ws;
    ushort* xf    = (ushort*)p; p += (size_t)kS * kD * 2;        // x f16
    ushort* wqkvf = (ushort*)p; p += (size_t)kNQKV * kD * 2;     // Wqkv f16
    ushort* woh   = (ushort*)p; p += (size_t)kD * kD * 2;
    ushort* wol   = (ushort*)p; p += (size_t)kD * kD * 2;
    float*  bqkv  = (float*)p;  p += 16384;
    ushort* qb16  = (ushort*)p; p += (size_t)kS * kD * 2;
    ushort* kb16  = (ushort*)p; p += (size_t)kS * kGHD * 2;
    ushort* vt16  = (ushort*)p; p += (size_t)kGHD * kS * 2;
    ushort* aoh   = (ushort*)p; p += (size_t)kS * kD * 2;
    ushort* aol   = (ushort*)p;

    cvt_f16<<<kS * kD / 1024, 256, 0, stream>>>(x, xf, kS * kD);
    cvt_f16<<<kD * kD / 1024, 256, 0, stream>>>(Wq, wqkvf, kD * kD);
    cvt_f16<<<kGHD * kD / 1024, 256, 0, stream>>>(Wk, wqkvf + (size_t)kD * kD, kGHD * kD);
    cvt_f16<<<kGHD * kD / 1024, 256, 0, stream>>>(
        Wv, wqkvf + (size_t)(kD + kGHD) * kD, kGHD * kD);
    cvt_split<<<kD * kD / 1024, 256, 0, stream>>>(Wo, woh, wol, kD * kD);

    hipMemcpyAsync(bqkv,             bq, kD   * 4, hipMemcpyDeviceToDevice, stream);
    hipMemcpyAsync(bqkv + kD,        bk, kGHD * 4, hipMemcpyDeviceToDevice, stream);
    hipMemcpyAsync(bqkv + kD + kGHD, bv, kGHD * 4, hipMemcpyDeviceToDevice, stream);

    // fused QKV projection (single-product f16) -> q,k row-major; v transposed
    gemm_qkv<<<dim3(kNQKV / 128, kS / 128), 256, 0, stream>>>(
        xf, wqkvf, bqkv, qb16, kb16, vt16, kD);

    // MFMA flash attention (8 waves/block, K/V double-buffered)
    gqa_attn_mfma<<<dim3(kS / 64, kG), 512, 0, stream>>>(qb16, kb16, vt16, aoh, aol);

    // output projection (split-bf16, fp32-accurate)
    gemm_o<<<dim3(kD / 128, kS / 128), 256, 0, stream>>>(
        aoh, aol, woh, wol, bo, out, kD, kD);
}

// Round 5
// 248.983 us; speedup vs baseline: 7.4855x; 1.1025x over previous
//
#include <hip/hip_runtime.h>
#include <hip/hip_bf16.h>

// Problem constants (B=1)
constexpr int kS   = 2048;
constexpr int kD   = 2048;
constexpr int kG   = 8;
constexpr int kHD  = 64;
constexpr int kGHD = 512;
constexpr int kNQKV = kD + 2 * kGHD;   // 3072 fused QKV output cols

typedef __attribute__((ext_vector_type(8))) _Float16 f16x8;
typedef __attribute__((ext_vector_type(4))) float    f32x4;

__device__ __forceinline__ ushort f2h(float x) {
    return __builtin_bit_cast(ushort, (_Float16)x);
}
__device__ __forceinline__ float h2f(ushort u) {
    return (float)__builtin_bit_cast(_Float16, u);
}

// ---------------------------------------------------------------------------
// fp32 -> f16 with scale (scale folds 1/sqrt(HD) into Wq)
// ---------------------------------------------------------------------------
__global__ __launch_bounds__(256) void cvt_f16(
    const float* __restrict__ in, ushort* __restrict__ out, int n, float scale)
{
    const int i = (blockIdx.x * 256 + threadIdx.x) * 4;
    if (i >= n) return;
    const float4 x = *(const float4*)&in[i];
    ushort4 o;
    o.x = f2h(x.x * scale); o.y = f2h(x.y * scale);
    o.z = f2h(x.z * scale); o.w = f2h(x.w * scale);
    *(ushort4*)&out[i] = o;
}

// ---------------------------------------------------------------------------
// fused bias vector: [bq*0.125 | bk | bv]
// ---------------------------------------------------------------------------
__global__ __launch_bounds__(256) void prep_bias(
    const float* __restrict__ bq, const float* __restrict__ bk,
    const float* __restrict__ bv, float* __restrict__ bqkv)
{
    const int i = blockIdx.x * 256 + threadIdx.x;
    if (i < kD)            bqkv[i] = bq[i] * 0.125f;
    else if (i < kD + kGHD) bqkv[i] = bk[i - kD];
    else if (i < kNQKV)     bqkv[i] = bv[i - kD - kGHD];
}

// ---------------------------------------------------------------------------
// XCD-bijective block swizzle (grids here are multiples of 8)
// ---------------------------------------------------------------------------
__device__ __forceinline__ int xcd_swizzle(int orig, int nwg) {
    const int cpx = nwg >> 3;              // nwg % 8 == 0 guaranteed by launch
    return (orig & 7) * cpx + (orig >> 3);
}

// ---------------------------------------------------------------------------
// Single-product f16 MFMA GEMM for QKV: C = A @ B^T + bias, outputs f16.
// q -> [S][D] (pre-scaled by 1/8 via Wq/bq), k -> [S][GHD], v -> [GHD][S]^T.
// ---------------------------------------------------------------------------
__global__ __launch_bounds__(256) void gemm_qkv(
    const ushort* __restrict__ Af, const ushort* __restrict__ Bf,
    const float* __restrict__ bias,
    ushort* __restrict__ qb16, ushort* __restrict__ kb16, ushort* __restrict__ vt16,
    int K, int gridX)
{
    __shared__ ushort lds[2][128 * 32];   // A | B f16 tiles

    const int bid  = xcd_swizzle(blockIdx.x, gridDim.x);
    const int m0   = (bid / gridX) * 128;
    const int n0   = (bid % gridX) * 128;
    const int tid  = threadIdx.x;
    const int wid  = tid >> 6;
    const int lane = tid & 63;
    const int wm   = wid >> 1;
    const int wn   = wid & 1;
    const int fr   = lane & 15;
    const int kq   = lane >> 4;

    const ushort* gsrc = (wid < 2) ? Af : Bf;
    const int  rbase = (wid < 2) ? m0 : n0;
    const size_t grow = (size_t)(rbase + (wid & 1) * 64 + (lane >> 2));
    const int    gofs = (lane & 3) * 8;
    const int    tsel = wid >> 1;
    const int    lofs = (wid & 1) * 2048;

    f32x4 acc[4][4];
    #pragma unroll
    for (int mi = 0; mi < 4; ++mi)
        #pragma unroll
        for (int ni = 0; ni < 4; ++ni) {
            f32x4 z = {0.f, 0.f, 0.f, 0.f};
            acc[mi][ni] = z;
        }

    for (int k0 = 0; k0 < K; k0 += 32) {
        __syncthreads();
        const ushort* gp = gsrc + grow * K + k0 + gofs;
        #pragma unroll
        for (int i = 0; i < 4; ++i) {
            __builtin_amdgcn_global_load_lds(
                (const __attribute__((address_space(1))) void*)(gp + (size_t)i * 16 * K),
                (__attribute__((address_space(3))) void*)&lds[tsel][lofs + i * 512],
                16, 0, 0);
        }
        __syncthreads();

        f16x8 af[4], bfr[4];
        #pragma unroll
        for (int f = 0; f < 4; ++f) {
            af[f]  = *(const f16x8*)&lds[0][(wm * 64 + f * 16 + fr) * 32 + kq * 8];
            bfr[f] = *(const f16x8*)&lds[1][(wn * 64 + f * 16 + fr) * 32 + kq * 8];
        }
        __builtin_amdgcn_s_setprio(1);
        #pragma unroll
        for (int mi = 0; mi < 4; ++mi)
            #pragma unroll
            for (int ni = 0; ni < 4; ++ni)
                acc[mi][ni] = __builtin_amdgcn_mfma_f32_16x16x32_f16(
                    af[mi], bfr[ni], acc[mi][ni], 0, 0, 0);
        __builtin_amdgcn_s_setprio(0);
    }

    const int seg = (n0 < kD) ? 0 : (n0 < kD + kGHD) ? 1 : 2;   // uniform per block
    #pragma unroll
    for (int ni = 0; ni < 4; ++ni) {
        const int ncol = n0 + wn * 64 + ni * 16 + fr;
        const float bv = bias[ncol];
        #pragma unroll
        for (int mi = 0; mi < 4; ++mi) {
            #pragma unroll
            for (int i = 0; i < 4; ++i) {
                const int row = m0 + wm * 64 + mi * 16 + kq * 4 + i;
                const ushort u = f2h(acc[mi][ni][i] + bv);
                if (seg == 0)      qb16[(size_t)row * kD   + ncol]              = u;
                else if (seg == 1) kb16[(size_t)row * kGHD + (ncol - kD)]       = u;
                else               vt16[(size_t)(ncol - kD - kGHD) * kS + row]  = u;
            }
        }
    }
}

// ---------------------------------------------------------------------------
// 2-product f16 MFMA GEMM for O-proj: out(fp32) = (Ah+Al) @ W^T + bias
// Ah/Al are exact f16 hi/lo split of attention output; W single f16.
// ---------------------------------------------------------------------------
__global__ __launch_bounds__(256) void gemm_o(
    const ushort* __restrict__ Ah, const ushort* __restrict__ Al,
    const ushort* __restrict__ Wf,
    const float* __restrict__ bias, float* __restrict__ C, int K, int N, int gridX)
{
    __shared__ ushort lds[3][128 * 32];   // Ah | Al | W tiles

    const int bid  = xcd_swizzle(blockIdx.x, gridDim.x);
    const int m0   = (bid / gridX) * 128;
    const int n0   = (bid % gridX) * 128;
    const int tid  = threadIdx.x;
    const int wid  = tid >> 6;
    const int lane = tid & 63;
    const int wm   = wid >> 1;
    const int wn   = wid & 1;
    const int fr   = lane & 15;
    const int kq   = lane >> 4;

    // staging: wave0 -> Ah (8 issues), wave1 -> Al (8), waves 2,3 -> W halves (4 each)
    const bool isA = (wid < 2);
    const ushort* gsrc = (wid == 0) ? Ah : (wid == 1) ? Al : Wf;
    const int  rbase = isA ? m0 : (n0 + (wid & 1) * 64);
    const size_t grow = (size_t)(rbase + (lane >> 2));
    const int    gofs = (lane & 3) * 8;
    const int    tsel = isA ? wid : 2;
    const int    lofs = isA ? 0 : (wid & 1) * 2048;
    const int    nIss = isA ? 8 : 4;

    f32x4 acc[4][4];
    #pragma unroll
    for (int mi = 0; mi < 4; ++mi)
        #pragma unroll
        for (int ni = 0; ni < 4; ++ni) {
            f32x4 z = {0.f, 0.f, 0.f, 0.f};
            acc[mi][ni] = z;
        }

    for (int k0 = 0; k0 < K; k0 += 32) {
        __syncthreads();
        const ushort* gp = gsrc + grow * K + k0 + gofs;
        #pragma unroll
        for (int i = 0; i < 8; ++i) {
            if (i < nIss)
                __builtin_amdgcn_global_load_lds(
                    (const __attribute__((address_space(1))) void*)(gp + (size_t)i * 16 * K),
                    (__attribute__((address_space(3))) void*)&lds[tsel][lofs + i * 512],
                    16, 0, 0);
        }
        __syncthreads();

        f16x8 ah[4], al[4], wf[4];
        #pragma unroll
        for (int f = 0; f < 4; ++f) {
            ah[f] = *(const f16x8*)&lds[0][(wm * 64 + f * 16 + fr) * 32 + kq * 8];
            al[f] = *(const f16x8*)&lds[1][(wm * 64 + f * 16 + fr) * 32 + kq * 8];
            wf[f] = *(const f16x8*)&lds[2][(wn * 64 + f * 16 + fr) * 32 + kq * 8];
        }
        __builtin_amdgcn_s_setprio(1);
        #pragma unroll
        for (int mi = 0; mi < 4; ++mi)
            #pragma unroll
            for (int ni = 0; ni < 4; ++ni) {
                acc[mi][ni] = __builtin_amdgcn_mfma_f32_16x16x32_f16(ah[mi], wf[ni], acc[mi][ni], 0, 0, 0);
                acc[mi][ni] = __builtin_amdgcn_mfma_f32_16x16x32_f16(al[mi], wf[ni], acc[mi][ni], 0, 0, 0);
            }
        __builtin_amdgcn_s_setprio(0);
    }

    #pragma unroll
    for (int ni = 0; ni < 4; ++ni) {
        const int ncol = wn * 64 + ni * 16 + fr;
        const float bv = bias[n0 + ncol];
        #pragma unroll
        for (int mi = 0; mi < 4; ++mi)
            #pragma unroll
            for (int i = 0; i < 4; ++i) {
                const int row = m0 + wm * 64 + mi * 16 + kq * 4 + i;
                C[(size_t)row * N + n0 + ncol] = acc[mi][ni][i] + bv;
            }
    }
}

// ---------------------------------------------------------------------------
// MFMA flash attention, f16 operands, fp32 accum. Q pre-scaled by 1/8.
// grid = (S/32, G) = 512 blocks (2/CU); block = 512 = 8 waves:
// wave w -> head hp=w&3, q-half qh=w>>2 (16 q-rows each).
// K/V tiles (64 kv rows) double-buffered, next tile's loads issued pre-compute.
// Output: f16 hi/lo in reference (hp g d) column layout.
// ---------------------------------------------------------------------------
__global__ __launch_bounds__(512) void gqa_attn_mfma(
    const ushort* __restrict__ qb,   // [S][D] f16 (prescaled)
    const ushort* __restrict__ kb,   // [S][GHD] f16
    const ushort* __restrict__ vt,   // [GHD][S] f16 (V transposed)
    ushort* __restrict__ oh, ushort* __restrict__ ol)
{
    __shared__ ushort Kt[2][64 * 64];   // swizzled [k-row][d], dbuf (16 KB)
    __shared__ ushort Vt[2][64 * 64];   // swizzled [d][k-col], dbuf (16 KB)
    __shared__ ushort Pt[8][16 * 64];   // per-wave swizzled [q][k]  (16 KB)

    const int g    = blockIdx.y;
    const int q0   = blockIdx.x * 32;
    const int tid  = threadIdx.x;
    const int w    = tid >> 6;
    const int lane = tid & 63;
    const int hp   = w & 3;
    const int qh   = w >> 2;
    const int fr   = lane & 15;
    const int lq   = lane >> 4;
    const int h    = g * 4 + hp;
    const int qbase = q0 + qh * 16;

    // staging assignment: wave w covers tile rows w*8 .. w*8+7
    const int r = w * 8 + (lane >> 3);
    const int s = (lane & 7) ^ (r & 7);    // pre-swizzled source slot

    // prologue: stage tile 0 into buf 0
    __builtin_amdgcn_global_load_lds(
        (const __attribute__((address_space(1))) void*)(kb + (size_t)r * kGHD + g * kHD + s * 8),
        (__attribute__((address_space(3))) void*)(Kt[0] + w * 512), 16, 0, 0);
    __builtin_amdgcn_global_load_lds(
        (const __attribute__((address_space(1))) void*)(vt + (size_t)(g * kHD + r) * kS + s * 8),
        (__attribute__((address_space(3))) void*)(Vt[0] + w * 512), 16, 0, 0);

    // hoist Q fragments (A-operand: lane&15 = q-row)
    f16x8 qf[2];
    #pragma unroll
    for (int ks = 0; ks < 2; ++ks)
        qf[ks] = *(const f16x8*)&qb[(size_t)(qbase + fr) * kD + h * kHD + ks * 32 + lq * 8];

    float mrow[4], lrow[4];
    #pragma unroll
    for (int i = 0; i < 4; ++i) { mrow[i] = -1e30f; lrow[i] = 0.f; }

    f32x4 oacc[4];
    #pragma unroll
    for (int ni = 0; ni < 4; ++ni) {
        f32x4 z = {0.f, 0.f, 0.f, 0.f};
        oacc[ni] = z;
    }

    int cur = 0;
    for (int t = 0; t < kS; t += 64) {
        __syncthreads();   // buf[cur] staged (vmcnt drained); buf[cur^1] reads done

        if (t + 64 < kS) {
            __builtin_amdgcn_global_load_lds(
                (const __attribute__((address_space(1))) void*)
                    (kb + (size_t)(t + 64 + r) * kGHD + g * kHD + s * 8),
                (__attribute__((address_space(3))) void*)(Kt[cur ^ 1] + w * 512), 16, 0, 0);
            __builtin_amdgcn_global_load_lds(
                (const __attribute__((address_space(1))) void*)
                    (vt + (size_t)(g * kHD + r) * kS + t + 64 + s * 8),
                (__attribute__((address_space(3))) void*)(Vt[cur ^ 1] + w * 512), 16, 0, 0);
        }

        // --- QK^T: S[16q x 64k] per wave (prescaled logits) ---
        f32x4 sc[4];
        #pragma unroll
        for (int ni = 0; ni < 4; ++ni) {
            f32x4 z = {0.f, 0.f, 0.f, 0.f};
            sc[ni] = z;
        }
        #pragma unroll
        for (int ks = 0; ks < 2; ++ks) {
            f16x8 kf[4];
            #pragma unroll
            for (int ni = 0; ni < 4; ++ni)
                kf[ni] = *(const f16x8*)&Kt[cur][(ni * 16 + fr) * 64
                                                 + (((ks * 4 + lq) ^ (fr & 7)) * 8)];
            __builtin_amdgcn_s_setprio(1);
            #pragma unroll
            for (int ni = 0; ni < 4; ++ni)
                sc[ni] = __builtin_amdgcn_mfma_f32_16x16x32_f16(
                    qf[ks], kf[ni], sc[ni], 0, 0, 0);
            __builtin_amdgcn_s_setprio(0);
        }

        // --- online softmax (4 rows per lane) ---
        #pragma unroll
        for (int i = 0; i < 4; ++i) {
            float mt = fmaxf(fmaxf(sc[0][i], sc[1][i]), fmaxf(sc[2][i], sc[3][i]));
            mt = fmaxf(mt, __shfl_xor(mt, 1));
            mt = fmaxf(mt, __shfl_xor(mt, 2));
            mt = fmaxf(mt, __shfl_xor(mt, 4));
            mt = fmaxf(mt, __shfl_xor(mt, 8));
            const float mnew = fmaxf(mrow[i], mt);
            const float c = __expf(mrow[i] - mnew);
            float ps = 0.f;
            #pragma unroll
            for (int ni = 0; ni < 4; ++ni) {
                const float p = __expf(sc[ni][i] - mnew);
                sc[ni][i] = p;
                ps += p;
            }
            ps += __shfl_xor(ps, 1);
            ps += __shfl_xor(ps, 2);
            ps += __shfl_xor(ps, 4);
            ps += __shfl_xor(ps, 8);
            lrow[i] = lrow[i] * c + ps;
            mrow[i] = mnew;
            #pragma unroll
            for (int ni = 0; ni < 4; ++ni)
                oacc[ni][i] *= c;
        }

        // --- P -> f16 -> swizzled per-wave LDS (same-wave RAW) ---
        #pragma unroll
        for (int i = 0; i < 4; ++i) {
            const int qr = lq * 4 + i;
            #pragma unroll
            for (int ni = 0; ni < 4; ++ni) {
                const int slot = (ni * 2 + (fr >> 3)) ^ (qr & 7);
                Pt[w][qr * 64 + slot * 8 + (fr & 7)] = f2h(sc[ni][i]);
            }
        }

        // --- PV: O += P @ V ---
        #pragma unroll
        for (int ks = 0; ks < 2; ++ks) {
            f16x8 pf, vf[4];
            pf = *(const f16x8*)&Pt[w][fr * 64 + (((ks * 4 + lq) ^ (fr & 7)) * 8)];
            #pragma unroll
            for (int ni = 0; ni < 4; ++ni)
                vf[ni] = *(const f16x8*)&Vt[cur][(ni * 16 + fr) * 64
                                                 + (((ks * 4 + lq) ^ (fr & 7)) * 8)];
            __builtin_amdgcn_s_setprio(1);
            #pragma unroll
            for (int ni = 0; ni < 4; ++ni)
                oacc[ni] = __builtin_amdgcn_mfma_f32_16x16x32_f16(
                    pf, vf[ni], oacc[ni], 0, 0, 0);
            __builtin_amdgcn_s_setprio(0);
        }
        cur ^= 1;
    }

    // --- finalize: O/l, f16 hi/lo split, reference (hp g d) layout ---
    #pragma unroll
    for (int i = 0; i < 4; ++i) {
        const float inv = 1.f / lrow[i];
        const size_t row = qbase + lq * 4 + i;
        #pragma unroll
        for (int ni = 0; ni < 4; ++ni) {
            const float o = oacc[ni][i] * inv;
            const ushort hv = f2h(o);
            const ushort lv = f2h(o - h2f(hv));
            const size_t addr = row * kD + hp * kGHD + g * kHD + ni * 16 + fr;
            oh[addr] = hv;
            ol[addr] = lv;
        }
    }
}

// ---------------------------------------------------------------------------
extern "C" void kernel_launch(void* const* d_in, const int* in_sizes, int n_in,
                              void* d_out, int out_size, void* d_ws, size_t ws_size,
                              hipStream_t stream)
{
    const float* x  = (const float*)d_in[0];
    const float* Wq = (const float*)d_in[1];
    const float* bq = (const float*)d_in[2];
    const float* Wk = (const float*)d_in[3];
    const float* bk = (const float*)d_in[4];
    const float* Wv = (const float*)d_in[5];
    const float* bv = (const float*)d_in[6];
    const float* Wo = (const float*)d_in[7];
    const float* bo = (const float*)d_in[8];
    float* out = (float*)d_out;

    // workspace layout (~56 MB)
    char* p = (char*)d_ws;
    ushort* xf    = (ushort*)p; p += (size_t)kS * kD * 2;        // x f16
    ushort* wqkvf = (ushort*)p; p += (size_t)kNQKV * kD * 2;     // Wqkv f16 (Wq pre-scaled)
    ushort* wof   = (ushort*)p; p += (size_t)kD * kD * 2;        // Wo f16
    float*  bqkv  = (float*)p;  p += 16384;
    ushort* qb16  = (ushort*)p; p += (size_t)kS * kD * 2;
    ushort* kb16  = (ushort*)p; p += (size_t)kS * kGHD * 2;
    ushort* vt16  = (ushort*)p; p += (size_t)kGHD * kS * 2;
    ushort* aoh   = (ushort*)p; p += (size_t)kS * kD * 2;        // attn out f16 hi
    ushort* aol   = (ushort*)p;                                  // attn out f16 lo

    cvt_f16<<<kS * kD / 1024, 256, 0, stream>>>(x, xf, kS * kD, 1.f);
    cvt_f16<<<kD * kD / 1024, 256, 0, stream>>>(Wq, wqkvf, kD * kD, 0.125f);
    cvt_f16<<<kGHD * kD / 1024, 256, 0, stream>>>(Wk, wqkvf + (size_t)kD * kD, kGHD * kD, 1.f);
    cvt_f16<<<kGHD * kD / 1024, 256, 0, stream>>>(
        Wv, wqkvf + (size_t)(kD + kGHD) * kD, kGHD * kD, 1.f);
    cvt_f16<<<kD * kD / 1024, 256, 0, stream>>>(Wo, wof, kD * kD, 1.f);
    prep_bias<<<(kNQKV + 255) / 256, 256, 0, stream>>>(bq, bk, bv, bqkv);

    // fused QKV projection (single f16) -> q(prescaled),k row-major; v transposed
    gemm_qkv<<<(kNQKV / 128) * (kS / 128), 256, 0, stream>>>(
        xf, wqkvf, bqkv, qb16, kb16, vt16, kD, kNQKV / 128);

    // MFMA flash attention (512 blocks, 8 waves each)
    gqa_attn_mfma<<<dim3(kS / 32, kG), 512, 0, stream>>>(qb16, kb16, vt16, aoh, aol);

    // output projection (2-product f16: exact A-split, f16 W)
    gemm_o<<<(kD / 128) * (kS / 128), 256, 0, stream>>>(
        aoh, aol, wof, bo, out, kD, kD, kD / 128);
}

// Round 7
// 204.297 us; speedup vs baseline: 9.1228x; 1.2187x over previous
//
#include <hip/hip_runtime.h>
#include <hip/hip_bf16.h>

// Problem constants (B=1)
constexpr int kS   = 2048;
constexpr int kD   = 2048;
constexpr int kG   = 8;
constexpr int kHD  = 64;
constexpr int kGHD = 512;
constexpr int kNQKV = kD + 2 * kGHD;   // 3072 fused QKV output cols

// 0.125 (1/sqrt(HD)) * log2(e): folds softmax scale AND exp->exp2 into Wq/bq
constexpr float kQScale = 0.125f * 1.4426950408889634f;

typedef __attribute__((ext_vector_type(8))) _Float16 f16x8;
typedef __attribute__((ext_vector_type(4))) float    f32x4;

__device__ __forceinline__ ushort f2h(float x) {
    return __builtin_bit_cast(ushort, (_Float16)x);
}
__device__ __forceinline__ float h2f(ushort u) {
    return (float)__builtin_bit_cast(_Float16, u);
}
// fast 2^x on the VALU (v_exp_f32 is base-2 per ISA)
__device__ __forceinline__ float fast_exp2(float x) {
    return __builtin_amdgcn_exp2f(x);
}

// ---------------------------------------------------------------------------
// fp32 -> f16 with scale
// ---------------------------------------------------------------------------
__global__ __launch_bounds__(256) void cvt_f16(
    const float* __restrict__ in, ushort* __restrict__ out, int n, float scale)
{
    const int i = (blockIdx.x * 256 + threadIdx.x) * 4;
    if (i >= n) return;
    const float4 x = *(const float4*)&in[i];
    ushort4 o;
    o.x = f2h(x.x * scale); o.y = f2h(x.y * scale);
    o.z = f2h(x.z * scale); o.w = f2h(x.w * scale);
    *(ushort4*)&out[i] = o;
}

// ---------------------------------------------------------------------------
// fused bias vector: [bq*kQScale | bk | bv]
// ---------------------------------------------------------------------------
__global__ __launch_bounds__(256) void prep_bias(
    const float* __restrict__ bq, const float* __restrict__ bk,
    const float* __restrict__ bv, float* __restrict__ bqkv)
{
    const int i = blockIdx.x * 256 + threadIdx.x;
    if (i < kD)             bqkv[i] = bq[i] * kQScale;
    else if (i < kD + kGHD) bqkv[i] = bk[i - kD];
    else if (i < kNQKV)     bqkv[i] = bv[i - kD - kGHD];
}

// ---------------------------------------------------------------------------
// XCD-bijective block swizzle (grids here are multiples of 8)
// ---------------------------------------------------------------------------
__device__ __forceinline__ int xcd_swizzle(int orig, int nwg) {
    const int cpx = nwg >> 3;
    return (orig & 7) * cpx + (orig >> 3);
}

// ---------------------------------------------------------------------------
// Single-product f16 MFMA GEMM for QKV: C = A @ B^T + bias, outputs f16.
// q -> [S][D] (pre-scaled), k -> [S][GHD], v -> [GHD][S]^T.
// ---------------------------------------------------------------------------
__global__ __launch_bounds__(256) void gemm_qkv(
    const ushort* __restrict__ Af, const ushort* __restrict__ Bf,
    const float* __restrict__ bias,
    ushort* __restrict__ qb16, ushort* __restrict__ kb16, ushort* __restrict__ vt16,
    int K, int gridX)
{
    __shared__ ushort lds[2][128 * 32];   // A | B f16 tiles

    const int bid  = xcd_swizzle(blockIdx.x, gridDim.x);
    const int m0   = (bid / gridX) * 128;
    const int n0   = (bid % gridX) * 128;
    const int tid  = threadIdx.x;
    const int wid  = tid >> 6;
    const int lane = tid & 63;
    const int wm   = wid >> 1;
    const int wn   = wid & 1;
    const int fr   = lane & 15;
    const int kq   = lane >> 4;

    const ushort* gsrc = (wid < 2) ? Af : Bf;
    const int  rbase = (wid < 2) ? m0 : n0;
    const size_t grow = (size_t)(rbase + (wid & 1) * 64 + (lane >> 2));
    const int    gofs = (lane & 3) * 8;
    const int    tsel = wid >> 1;
    const int    lofs = (wid & 1) * 2048;

    f32x4 acc[4][4];
    #pragma unroll
    for (int mi = 0; mi < 4; ++mi)
        #pragma unroll
        for (int ni = 0; ni < 4; ++ni) {
            f32x4 z = {0.f, 0.f, 0.f, 0.f};
            acc[mi][ni] = z;
        }

    for (int k0 = 0; k0 < K; k0 += 32) {
        __syncthreads();
        const ushort* gp = gsrc + grow * K + k0 + gofs;
        #pragma unroll
        for (int i = 0; i < 4; ++i) {
            __builtin_amdgcn_global_load_lds(
                (const __attribute__((address_space(1))) void*)(gp + (size_t)i * 16 * K),
                (__attribute__((address_space(3))) void*)&lds[tsel][lofs + i * 512],
                16, 0, 0);
        }
        __syncthreads();

        f16x8 af[4], bfr[4];
        #pragma unroll
        for (int f = 0; f < 4; ++f) {
            af[f]  = *(const f16x8*)&lds[0][(wm * 64 + f * 16 + fr) * 32 + kq * 8];
            bfr[f] = *(const f16x8*)&lds[1][(wn * 64 + f * 16 + fr) * 32 + kq * 8];
        }
        __builtin_amdgcn_s_setprio(1);
        #pragma unroll
        for (int mi = 0; mi < 4; ++mi)
            #pragma unroll
            for (int ni = 0; ni < 4; ++ni)
                acc[mi][ni] = __builtin_amdgcn_mfma_f32_16x16x32_f16(
                    af[mi], bfr[ni], acc[mi][ni], 0, 0, 0);
        __builtin_amdgcn_s_setprio(0);
    }

    const int seg = (n0 < kD) ? 0 : (n0 < kD + kGHD) ? 1 : 2;   // uniform per block
    #pragma unroll
    for (int ni = 0; ni < 4; ++ni) {
        const int ncol = n0 + wn * 64 + ni * 16 + fr;
        const float bv = bias[ncol];
        #pragma unroll
        for (int mi = 0; mi < 4; ++mi) {
            #pragma unroll
            for (int i = 0; i < 4; ++i) {
                const int row = m0 + wm * 64 + mi * 16 + kq * 4 + i;
                const ushort u = f2h(acc[mi][ni][i] + bv);
                if (seg == 0)      qb16[(size_t)row * kD   + ncol]              = u;
                else if (seg == 1) kb16[(size_t)row * kGHD + (ncol - kD)]       = u;
                else               vt16[(size_t)(ncol - kD - kGHD) * kS + row]  = u;
            }
        }
    }
}

// ---------------------------------------------------------------------------
// 2-product f16 MFMA GEMM for O-proj: out(fp32) = (Ah+Al) @ W^T + bias
// ---------------------------------------------------------------------------
__global__ __launch_bounds__(256) void gemm_o(
    const ushort* __restrict__ Ah, const ushort* __restrict__ Al,
    const ushort* __restrict__ Wf,
    const float* __restrict__ bias, float* __restrict__ C, int K, int N, int gridX)
{
    __shared__ ushort lds[3][128 * 32];   // Ah | Al | W tiles

    const int bid  = xcd_swizzle(blockIdx.x, gridDim.x);
    const int m0   = (bid / gridX) * 128;
    const int n0   = (bid % gridX) * 128;
    const int tid  = threadIdx.x;
    const int wid  = tid >> 6;
    const int lane = tid & 63;
    const int wm   = wid >> 1;
    const int wn   = wid & 1;
    const int fr   = lane & 15;
    const int kq   = lane >> 4;

    const bool isA = (wid < 2);
    const ushort* gsrc = (wid == 0) ? Ah : (wid == 1) ? Al : Wf;
    const int  rbase = isA ? m0 : (n0 + (wid & 1) * 64);
    const size_t grow = (size_t)(rbase + (lane >> 2));
    const int    gofs = (lane & 3) * 8;
    const int    tsel = isA ? wid : 2;
    const int    lofs = isA ? 0 : (wid & 1) * 2048;
    const int    nIss = isA ? 8 : 4;

    f32x4 acc[4][4];
    #pragma unroll
    for (int mi = 0; mi < 4; ++mi)
        #pragma unroll
        for (int ni = 0; ni < 4; ++ni) {
            f32x4 z = {0.f, 0.f, 0.f, 0.f};
            acc[mi][ni] = z;
        }

    for (int k0 = 0; k0 < K; k0 += 32) {
        __syncthreads();
        const ushort* gp = gsrc + grow * K + k0 + gofs;
        #pragma unroll
        for (int i = 0; i < 8; ++i) {
            if (i < nIss)
                __builtin_amdgcn_global_load_lds(
                    (const __attribute__((address_space(1))) void*)(gp + (size_t)i * 16 * K),
                    (__attribute__((address_space(3))) void*)&lds[tsel][lofs + i * 512],
                    16, 0, 0);
        }
        __syncthreads();

        f16x8 ah[4], al[4], wf[4];
        #pragma unroll
        for (int f = 0; f < 4; ++f) {
            ah[f] = *(const f16x8*)&lds[0][(wm * 64 + f * 16 + fr) * 32 + kq * 8];
            al[f] = *(const f16x8*)&lds[1][(wm * 64 + f * 16 + fr) * 32 + kq * 8];
            wf[f] = *(const f16x8*)&lds[2][(wn * 64 + f * 16 + fr) * 32 + kq * 8];
        }
        __builtin_amdgcn_s_setprio(1);
        #pragma unroll
        for (int mi = 0; mi < 4; ++mi)
            #pragma unroll
            for (int ni = 0; ni < 4; ++ni) {
                acc[mi][ni] = __builtin_amdgcn_mfma_f32_16x16x32_f16(ah[mi], wf[ni], acc[mi][ni], 0, 0, 0);
                acc[mi][ni] = __builtin_amdgcn_mfma_f32_16x16x32_f16(al[mi], wf[ni], acc[mi][ni], 0, 0, 0);
            }
        __builtin_amdgcn_s_setprio(0);
    }

    #pragma unroll
    for (int ni = 0; ni < 4; ++ni) {
        const int ncol = wn * 64 + ni * 16 + fr;
        const float bv = bias[n0 + ncol];
        #pragma unroll
        for (int mi = 0; mi < 4; ++mi)
            #pragma unroll
            for (int i = 0; i < 4; ++i) {
                const int row = m0 + wm * 64 + mi * 16 + kq * 4 + i;
                C[(size_t)row * N + n0 + ncol] = acc[mi][ni][i] + bv;
            }
    }
}

// ---------------------------------------------------------------------------
// MFMA flash attention, f16 operands, fp32 accum. Q pre-scaled into log2 domain.
// grid = (S/32, G) = 512 blocks; block = 512 = 8 waves (head hp=w&3, qh=w>>2).
// SWAPPED QK^T: sc = mfma(K, Q) -> S^T[k][q]; lane holds 16 k-values for ONE
// q-row (q = lane&15) -> in-lane softmax reduce (2 shfls instead of 8/row).
// Defer-max (T13): skip O-rescale unless tile max exceeds running max by 11.5
// (log2 domain; P <= 2^11.5 fits f16). K/V double-buffered via global_load_lds.
// ---------------------------------------------------------------------------
__global__ __launch_bounds__(512) void gqa_attn_mfma(
    const ushort* __restrict__ qb,   // [S][D] f16 (prescaled by kQScale)
    const ushort* __restrict__ kb,   // [S][GHD] f16
    const ushort* __restrict__ vt,   // [GHD][S] f16 (V transposed)
    ushort* __restrict__ oh, ushort* __restrict__ ol)
{
    __shared__ ushort Kt[2][64 * 64];   // swizzled [k-row][d], dbuf (16 KB)
    __shared__ ushort Vt[2][64 * 64];   // swizzled [d][k-col], dbuf (16 KB)
    __shared__ ushort Pt[8][16 * 64];   // per-wave swizzled [q][k]  (16 KB)

    const int g    = blockIdx.y;
    const int q0   = blockIdx.x * 32;
    const int tid  = threadIdx.x;
    const int w    = tid >> 6;
    const int lane = tid & 63;
    const int hp   = w & 3;
    const int qh   = w >> 2;
    const int fr   = lane & 15;
    const int lq   = lane >> 4;
    const int h    = g * 4 + hp;
    const int qbase = q0 + qh * 16;

    // staging assignment: wave w covers tile rows w*8 .. w*8+7
    const int r = w * 8 + (lane >> 3);
    const int s = (lane & 7) ^ (r & 7);    // pre-swizzled source slot

    // prologue: stage tile 0 into buf 0
    __builtin_amdgcn_global_load_lds(
        (const __attribute__((address_space(1))) void*)(kb + (size_t)r * kGHD + g * kHD + s * 8),
        (__attribute__((address_space(3))) void*)(Kt[0] + w * 512), 16, 0, 0);
    __builtin_amdgcn_global_load_lds(
        (const __attribute__((address_space(1))) void*)(vt + (size_t)(g * kHD + r) * kS + s * 8),
        (__attribute__((address_space(3))) void*)(Vt[0] + w * 512), 16, 0, 0);

    // hoist Q fragments (B-operand now: lane&15 = q-col; layout identical to A)
    f16x8 qf[2];
    #pragma unroll
    for (int ks = 0; ks < 2; ++ks)
        qf[ks] = *(const f16x8*)&qb[(size_t)(qbase + fr) * kD + h * kHD + ks * 32 + lq * 8];

    float mrow = -1e30f, lrow = 0.f;   // stats for q-row (qbase + fr)

    f32x4 oacc[4];
    #pragma unroll
    for (int ni = 0; ni < 4; ++ni) {
        f32x4 z = {0.f, 0.f, 0.f, 0.f};
        oacc[ni] = z;
    }

    int cur = 0;
    for (int t = 0; t < kS; t += 64) {
        __syncthreads();   // buf[cur] staged (vmcnt drained); buf[cur^1] reads done

        if (t + 64 < kS) {
            __builtin_amdgcn_global_load_lds(
                (const __attribute__((address_space(1))) void*)
                    (kb + (size_t)(t + 64 + r) * kGHD + g * kHD + s * 8),
                (__attribute__((address_space(3))) void*)(Kt[cur ^ 1] + w * 512), 16, 0, 0);
            __builtin_amdgcn_global_load_lds(
                (const __attribute__((address_space(1))) void*)
                    (vt + (size_t)(g * kHD + r) * kS + t + 64 + s * 8),
                (__attribute__((address_space(3))) void*)(Vt[cur ^ 1] + w * 512), 16, 0, 0);
        }

        // --- swapped QK^T: sc[ni][i] = S^T[k = ni*16 + lq*4 + i][q = fr] ---
        f32x4 sc[4];
        #pragma unroll
        for (int ni = 0; ni < 4; ++ni) {
            f32x4 z = {0.f, 0.f, 0.f, 0.f};
            sc[ni] = z;
        }
        #pragma unroll
        for (int ks = 0; ks < 2; ++ks) {
            f16x8 kf[4];
            #pragma unroll
            for (int ni = 0; ni < 4; ++ni)
                kf[ni] = *(const f16x8*)&Kt[cur][(ni * 16 + fr) * 64
                                                 + (((ks * 4 + lq) ^ (fr & 7)) * 8)];
            __builtin_amdgcn_s_setprio(1);
            #pragma unroll
            for (int ni = 0; ni < 4; ++ni)
                sc[ni] = __builtin_amdgcn_mfma_f32_16x16x32_f16(
                    kf[ni], qf[ks], sc[ni], 0, 0, 0);
            __builtin_amdgcn_s_setprio(0);
        }

        // --- in-lane softmax over 16 k-values + 2 shfls across lq groups ---
        float mt = sc[0][0];
        #pragma unroll
        for (int ni = 0; ni < 4; ++ni)
            #pragma unroll
            for (int i = 0; i < 4; ++i)
                mt = fmaxf(mt, sc[ni][i]);
        mt = fmaxf(mt, __shfl_xor(mt, 16));
        mt = fmaxf(mt, __shfl_xor(mt, 32));

        // defer-max: rescale only when tile max exceeds running max by >11.5
        if (__any(mt > mrow + 11.5f)) {
            const float mnew = (mt > mrow + 11.5f) ? mt : mrow;
            const float c = fast_exp2(mrow - mnew);   // 1.0 for untriggered lanes
            lrow *= c;
            mrow = mnew;
            #pragma unroll
            for (int i = 0; i < 4; ++i) {
                const float ci = __shfl(c, lq * 4 + i);   // c lives at lane q
                #pragma unroll
                for (int ni = 0; ni < 4; ++ni)
                    oacc[ni][i] *= ci;
            }
        }

        float ps = 0.f;
        #pragma unroll
        for (int ni = 0; ni < 4; ++ni)
            #pragma unroll
            for (int i = 0; i < 4; ++i) {
                const float p = fast_exp2(sc[ni][i] - mrow);
                sc[ni][i] = p;
                ps += p;
            }
        ps += __shfl_xor(ps, 16);
        ps += __shfl_xor(ps, 32);
        lrow += ps;

        // --- P^T in regs -> P[q][k] in LDS (4 packed ds_write_b64 per lane) ---
        #pragma unroll
        for (int ni = 0; ni < 4; ++ni) {
            const int kg0  = ni * 16 + lq * 4;            // 4 consecutive k
            const int slot = (kg0 >> 3) ^ (fr & 7);
            ushort4 pk;
            pk.x = f2h(sc[ni][0]); pk.y = f2h(sc[ni][1]);
            pk.z = f2h(sc[ni][2]); pk.w = f2h(sc[ni][3]);
            *(ushort4*)&Pt[w][fr * 64 + slot * 8 + (kg0 & 7)] = pk;
        }

        // --- PV: O += P @ V (same-wave LDS RAW; lgkmcnt orders) ---
        #pragma unroll
        for (int ks = 0; ks < 2; ++ks) {
            f16x8 pf, vf[4];
            pf = *(const f16x8*)&Pt[w][fr * 64 + (((ks * 4 + lq) ^ (fr & 7)) * 8)];
            #pragma unroll
            for (int ni = 0; ni < 4; ++ni)
                vf[ni] = *(const f16x8*)&Vt[cur][(ni * 16 + fr) * 64
                                                 + (((ks * 4 + lq) ^ (fr & 7)) * 8)];
            __builtin_amdgcn_s_setprio(1);
            #pragma unroll
            for (int ni = 0; ni < 4; ++ni)
                oacc[ni] = __builtin_amdgcn_mfma_f32_16x16x32_f16(
                    pf, vf[ni], oacc[ni], 0, 0, 0);
            __builtin_amdgcn_s_setprio(0);
        }
        cur ^= 1;
    }

    // --- finalize: O/l (1/l redistributed via shfl), f16 hi/lo split ---
    const float inv = 1.f / lrow;   // valid for q = qbase + fr
    #pragma unroll
    for (int i = 0; i < 4; ++i) {
        const float invi = __shfl(inv, lq * 4 + i);
        const size_t row = qbase + lq * 4 + i;
        #pragma unroll
        for (int ni = 0; ni < 4; ++ni) {
            const float o = oacc[ni][i] * invi;
            const ushort hv = f2h(o);
            const ushort lv = f2h(o - h2f(hv));
            const size_t addr = row * kD + hp * kGHD + g * kHD + ni * 16 + fr;
            oh[addr] = hv;
            ol[addr] = lv;
        }
    }
}

// ---------------------------------------------------------------------------
extern "C" void kernel_launch(void* const* d_in, const int* in_sizes, int n_in,
                              void* d_out, int out_size, void* d_ws, size_t ws_size,
                              hipStream_t stream)
{
    const float* x  = (const float*)d_in[0];
    const float* Wq = (const float*)d_in[1];
    const float* bq = (const float*)d_in[2];
    const float* Wk = (const float*)d_in[3];
    const float* bk = (const float*)d_in[4];
    const float* Wv = (const float*)d_in[5];
    const float* bv = (const float*)d_in[6];
    const float* Wo = (const float*)d_in[7];
    const float* bo = (const float*)d_in[8];
    float* out = (float*)d_out;

    // workspace layout (~56 MB)
    char* p = (char*)d_ws;
    ushort* xf    = (ushort*)p; p += (size_t)kS * kD * 2;        // x f16
    ushort* wqkvf = (ushort*)p; p += (size_t)kNQKV * kD * 2;     // Wqkv f16 (Wq pre-scaled)
    ushort* wof   = (ushort*)p; p += (size_t)kD * kD * 2;        // Wo f16
    float*  bqkv  = (float*)p;  p += 16384;
    ushort* qb16  = (ushort*)p; p += (size_t)kS * kD * 2;
    ushort* kb16  = (ushort*)p; p += (size_t)kS * kGHD * 2;
    ushort* vt16  = (ushort*)p; p += (size_t)kGHD * kS * 2;
    ushort* aoh   = (ushort*)p; p += (size_t)kS * kD * 2;        // attn out f16 hi
    ushort* aol   = (ushort*)p;                                  // attn out f16 lo

    cvt_f16<<<kS * kD / 1024, 256, 0, stream>>>(x, xf, kS * kD, 1.f);
    cvt_f16<<<kD * kD / 1024, 256, 0, stream>>>(Wq, wqkvf, kD * kD, kQScale);
    cvt_f16<<<kGHD * kD / 1024, 256, 0, stream>>>(Wk, wqkvf + (size_t)kD * kD, kGHD * kD, 1.f);
    cvt_f16<<<kGHD * kD / 1024, 256, 0, stream>>>(
        Wv, wqkvf + (size_t)(kD + kGHD) * kD, kGHD * kD, 1.f);
    cvt_f16<<<kD * kD / 1024, 256, 0, stream>>>(Wo, wof, kD * kD, 1.f);
    prep_bias<<<(kNQKV + 255) / 256, 256, 0, stream>>>(bq, bk, bv, bqkv);

    // fused QKV projection (single f16) -> q(prescaled),k row-major; v transposed
    gemm_qkv<<<(kNQKV / 128) * (kS / 128), 256, 0, stream>>>(
        xf, wqkvf, bqkv, qb16, kb16, vt16, kD, kNQKV / 128);

    // MFMA flash attention (swapped QK^T, in-lane softmax, defer-max)
    gqa_attn_mfma<<<dim3(kS / 32, kG), 512, 0, stream>>>(qb16, kb16, vt16, aoh, aol);

    // output projection (2-product f16: exact A-split, f16 W)
    gemm_o<<<(kD / 128) * (kS / 128), 256, 0, stream>>>(
        aoh, aol, wof, bo, out, kD, kD, kD / 128);
}

// Round 8
// 154.047 us; speedup vs baseline: 12.0987x; 1.3262x over previous
//
#include <hip/hip_runtime.h>
#include <hip/hip_bf16.h>

// Problem constants (B=1)
constexpr int kS   = 2048;
constexpr int kD   = 2048;
constexpr int kG   = 8;
constexpr int kHD  = 64;
constexpr int kGHD = 512;
constexpr int kNQKV = kD + 2 * kGHD;   // 3072 fused QKV output cols

// 0.125 (1/sqrt(HD)) * log2(e): folds softmax scale AND exp->exp2 into Wq/bq
constexpr float kQScale = 0.125f * 1.4426950408889634f;

typedef __attribute__((ext_vector_type(8))) _Float16 f16x8;
typedef __attribute__((ext_vector_type(4))) float    f32x4;

__device__ __forceinline__ ushort f2h(float x) {
    return __builtin_bit_cast(ushort, (_Float16)x);
}
__device__ __forceinline__ float h2f(ushort u) {
    return (float)__builtin_bit_cast(_Float16, u);
}
__device__ __forceinline__ float fast_exp2(float x) {
    return __builtin_amdgcn_exp2f(x);   // v_exp_f32 is base-2
}

// ---------------------------------------------------------------------------
// fp32 -> f16 with scale
// ---------------------------------------------------------------------------
__global__ __launch_bounds__(256) void cvt_f16(
    const float* __restrict__ in, ushort* __restrict__ out, int n, float scale)
{
    const int i = (blockIdx.x * 256 + threadIdx.x) * 4;
    if (i >= n) return;
    const float4 x = *(const float4*)&in[i];
    ushort4 o;
    o.x = f2h(x.x * scale); o.y = f2h(x.y * scale);
    o.z = f2h(x.z * scale); o.w = f2h(x.w * scale);
    *(ushort4*)&out[i] = o;
}

// ---------------------------------------------------------------------------
// fused bias vector: [bq*kQScale | bk | bv]
// ---------------------------------------------------------------------------
__global__ __launch_bounds__(256) void prep_bias(
    const float* __restrict__ bq, const float* __restrict__ bk,
    const float* __restrict__ bv, float* __restrict__ bqkv)
{
    const int i = blockIdx.x * 256 + threadIdx.x;
    if (i < kD)             bqkv[i] = bq[i] * kQScale;
    else if (i < kD + kGHD) bqkv[i] = bk[i - kD];
    else if (i < kNQKV)     bqkv[i] = bv[i - kD - kGHD];
}

// ---------------------------------------------------------------------------
// XCD-bijective block swizzle (grids here are multiples of 8)
// ---------------------------------------------------------------------------
__device__ __forceinline__ int xcd_swizzle(int orig, int nwg) {
    const int cpx = nwg >> 3;
    return (orig & 7) * cpx + (orig >> 3);
}

// ---------------------------------------------------------------------------
// Shared 8-wave 128x128 f16 GEMM structure, BK=32, 1-deep LDS prefetch:
//   prologue stage(buf0); loop { stage(buf^1, next); ds_read+MFMA(buf);
//   barrier (drains prefetch under this tile's compute); }
// LDS XOR-swizzle both-sides (rule #21): linear dest, source slot
// ^(lane>>3)&3, read slot kq^((fr>>1)&3) -> 2-way (free) read conflicts.
// Wave grid 2x4: per-wave 64x32 output, 8 MFMA/K-step.
// ---------------------------------------------------------------------------
#define GEMM_PRELUDE(Aptr, Bptr)                                              \
    const int bid  = xcd_swizzle(blockIdx.x, gridDim.x);                      \
    const int m0   = (bid / gridX) * 128;                                     \
    const int n0   = (bid % gridX) * 128;                                     \
    const int tid  = threadIdx.x;                                             \
    const int w    = tid >> 6;                                                \
    const int lane = tid & 63;                                                \
    const int wm   = w >> 2;                                                  \
    const int wn   = w & 3;                                                   \
    const int fr   = lane & 15;                                               \
    const int kq   = lane >> 4;                                               \
    const int srow = w * 16 + (lane >> 2);                                    \
    const int sslot = ((lane & 3) ^ ((lane >> 3) & 3)) * 8;                   \
    const ushort* gA = (Aptr) + (size_t)(m0 + srow) * K + sslot;              \
    const ushort* gB = (Bptr) + (size_t)(n0 + srow) * K + sslot;              \
    const int pslot = (kq ^ ((fr >> 1) & 3)) * 8;                             \
    f32x4 acc[4][2];                                                          \
    _Pragma("unroll")                                                         \
    for (int mi = 0; mi < 4; ++mi)                                            \
        _Pragma("unroll")                                                     \
        for (int ni = 0; ni < 2; ++ni) {                                      \
            f32x4 z = {0.f, 0.f, 0.f, 0.f};                                   \
            acc[mi][ni] = z;                                                  \
        }

#define GEMM_STAGE(buf, k0)                                                   \
    do {                                                                      \
        __builtin_amdgcn_global_load_lds(                                     \
            (const __attribute__((address_space(1))) void*)(gA + (k0)),       \
            (__attribute__((address_space(3))) void*)&lds[buf][0][w * 512],   \
            16, 0, 0);                                                        \
        __builtin_amdgcn_global_load_lds(                                     \
            (const __attribute__((address_space(1))) void*)(gB + (k0)),       \
            (__attribute__((address_space(3))) void*)&lds[buf][1][w * 512],   \
            16, 0, 0);                                                        \
    } while (0)

#define GEMM_KLOOP(MFMA_BODY)                                                 \
    GEMM_STAGE(0, 0);                                                         \
    __syncthreads();                                                          \
    int cur = 0;                                                              \
    for (int k0 = 0; k0 < K; k0 += 32) {                                      \
        if (k0 + 32 < K) GEMM_STAGE(cur ^ 1, k0 + 32);                        \
        f16x8 af[4], bf[2];                                                   \
        _Pragma("unroll")                                                     \
        for (int f = 0; f < 4; ++f)                                           \
            af[f] = *(const f16x8*)&lds[cur][0][(wm * 64 + f * 16 + fr) * 32 + pslot]; \
        _Pragma("unroll")                                                     \
        for (int f = 0; f < 2; ++f)                                           \
            bf[f] = *(const f16x8*)&lds[cur][1][(wn * 32 + f * 16 + fr) * 32 + pslot]; \
        __builtin_amdgcn_s_setprio(1);                                        \
        MFMA_BODY                                                             \
        __builtin_amdgcn_s_setprio(0);                                        \
        __syncthreads();                                                      \
        cur ^= 1;                                                             \
    }

// ---------------------------------------------------------------------------
// QKV GEMM: C = A @ B^T + bias -> f16; q [S][D], k [S][GHD], v^T [GHD][S]
// ---------------------------------------------------------------------------
__global__ __launch_bounds__(512) void gemm_qkv(
    const ushort* __restrict__ Af, const ushort* __restrict__ Bf,
    const float* __restrict__ bias,
    ushort* __restrict__ qb16, ushort* __restrict__ kb16, ushort* __restrict__ vt16,
    int K, int gridX)
{
    __shared__ ushort lds[2][2][128 * 32];   // [buf][A/B], 32 KB

    GEMM_PRELUDE(Af, Bf)
    GEMM_KLOOP(
        _Pragma("unroll")
        for (int mi = 0; mi < 4; ++mi)
            _Pragma("unroll")
            for (int ni = 0; ni < 2; ++ni)
                acc[mi][ni] = __builtin_amdgcn_mfma_f32_16x16x32_f16(
                    af[mi], bf[ni], acc[mi][ni], 0, 0, 0);
    )

    const int seg = (n0 < kD) ? 0 : (n0 < kD + kGHD) ? 1 : 2;   // uniform per block
    #pragma unroll
    for (int ni = 0; ni < 2; ++ni) {
        const int ncol = n0 + wn * 32 + ni * 16 + fr;
        const float bv = bias[ncol];
        #pragma unroll
        for (int mi = 0; mi < 4; ++mi) {
            #pragma unroll
            for (int i = 0; i < 4; ++i) {
                const int row = m0 + wm * 64 + mi * 16 + kq * 4 + i;
                const ushort u = f2h(acc[mi][ni][i] + bv);
                if (seg == 0)      qb16[(size_t)row * kD   + ncol]              = u;
                else if (seg == 1) kb16[(size_t)row * kGHD + (ncol - kD)]       = u;
                else               vt16[(size_t)(ncol - kD - kGHD) * kS + row]  = u;
            }
        }
    }
}

// ---------------------------------------------------------------------------
// O-proj GEMM: out(fp32) = A @ W^T + bias  (single-f16 A: margin analysis R8)
// ---------------------------------------------------------------------------
__global__ __launch_bounds__(512) void gemm_o(
    const ushort* __restrict__ Af, const ushort* __restrict__ Bf,
    const float* __restrict__ bias, float* __restrict__ C, int K, int N, int gridX)
{
    __shared__ ushort lds[2][2][128 * 32];

    GEMM_PRELUDE(Af, Bf)
    GEMM_KLOOP(
        _Pragma("unroll")
        for (int mi = 0; mi < 4; ++mi)
            _Pragma("unroll")
            for (int ni = 0; ni < 2; ++ni)
                acc[mi][ni] = __builtin_amdgcn_mfma_f32_16x16x32_f16(
                    af[mi], bf[ni], acc[mi][ni], 0, 0, 0);
    )

    #pragma unroll
    for (int ni = 0; ni < 2; ++ni) {
        const int ncol = n0 + wn * 32 + ni * 16 + fr;
        const float bv = bias[ncol];
        #pragma unroll
        for (int mi = 0; mi < 4; ++mi)
            #pragma unroll
            for (int i = 0; i < 4; ++i) {
                const int row = m0 + wm * 64 + mi * 16 + kq * 4 + i;
                C[(size_t)row * N + ncol] = acc[mi][ni][i] + bv;
            }
    }
}

// ---------------------------------------------------------------------------
// MFMA flash attention (unchanged from R7 except: single f16 output, no lo).
// ---------------------------------------------------------------------------
__global__ __launch_bounds__(512) void gqa_attn_mfma(
    const ushort* __restrict__ qb,   // [S][D] f16 (prescaled by kQScale)
    const ushort* __restrict__ kb,   // [S][GHD] f16
    const ushort* __restrict__ vt,   // [GHD][S] f16 (V transposed)
    ushort* __restrict__ oh)
{
    __shared__ ushort Kt[2][64 * 64];
    __shared__ ushort Vt[2][64 * 64];
    __shared__ ushort Pt[8][16 * 64];

    const int g    = blockIdx.y;
    const int q0   = blockIdx.x * 32;
    const int tid  = threadIdx.x;
    const int w    = tid >> 6;
    const int lane = tid & 63;
    const int hp   = w & 3;
    const int qh   = w >> 2;
    const int fr   = lane & 15;
    const int lq   = lane >> 4;
    const int h    = g * 4 + hp;
    const int qbase = q0 + qh * 16;

    const int r = w * 8 + (lane >> 3);
    const int s = (lane & 7) ^ (r & 7);

    __builtin_amdgcn_global_load_lds(
        (const __attribute__((address_space(1))) void*)(kb + (size_t)r * kGHD + g * kHD + s * 8),
        (__attribute__((address_space(3))) void*)(Kt[0] + w * 512), 16, 0, 0);
    __builtin_amdgcn_global_load_lds(
        (const __attribute__((address_space(1))) void*)(vt + (size_t)(g * kHD + r) * kS + s * 8),
        (__attribute__((address_space(3))) void*)(Vt[0] + w * 512), 16, 0, 0);

    f16x8 qf[2];
    #pragma unroll
    for (int ks = 0; ks < 2; ++ks)
        qf[ks] = *(const f16x8*)&qb[(size_t)(qbase + fr) * kD + h * kHD + ks * 32 + lq * 8];

    float mrow = -1e30f, lrow = 0.f;

    f32x4 oacc[4];
    #pragma unroll
    for (int ni = 0; ni < 4; ++ni) {
        f32x4 z = {0.f, 0.f, 0.f, 0.f};
        oacc[ni] = z;
    }

    int cur = 0;
    for (int t = 0; t < kS; t += 64) {
        __syncthreads();

        if (t + 64 < kS) {
            __builtin_amdgcn_global_load_lds(
                (const __attribute__((address_space(1))) void*)
                    (kb + (size_t)(t + 64 + r) * kGHD + g * kHD + s * 8),
                (__attribute__((address_space(3))) void*)(Kt[cur ^ 1] + w * 512), 16, 0, 0);
            __builtin_amdgcn_global_load_lds(
                (const __attribute__((address_space(1))) void*)
                    (vt + (size_t)(g * kHD + r) * kS + t + 64 + s * 8),
                (__attribute__((address_space(3))) void*)(Vt[cur ^ 1] + w * 512), 16, 0, 0);
        }

        // swapped QK^T: sc[ni][i] = S^T[k = ni*16 + lq*4 + i][q = fr]
        f32x4 sc[4];
        #pragma unroll
        for (int ni = 0; ni < 4; ++ni) {
            f32x4 z = {0.f, 0.f, 0.f, 0.f};
            sc[ni] = z;
        }
        #pragma unroll
        for (int ks = 0; ks < 2; ++ks) {
            f16x8 kf[4];
            #pragma unroll
            for (int ni = 0; ni < 4; ++ni)
                kf[ni] = *(const f16x8*)&Kt[cur][(ni * 16 + fr) * 64
                                                 + (((ks * 4 + lq) ^ (fr & 7)) * 8)];
            __builtin_amdgcn_s_setprio(1);
            #pragma unroll
            for (int ni = 0; ni < 4; ++ni)
                sc[ni] = __builtin_amdgcn_mfma_f32_16x16x32_f16(
                    kf[ni], qf[ks], sc[ni], 0, 0, 0);
            __builtin_amdgcn_s_setprio(0);
        }

        float mt = sc[0][0];
        #pragma unroll
        for (int ni = 0; ni < 4; ++ni)
            #pragma unroll
            for (int i = 0; i < 4; ++i)
                mt = fmaxf(mt, sc[ni][i]);
        mt = fmaxf(mt, __shfl_xor(mt, 16));
        mt = fmaxf(mt, __shfl_xor(mt, 32));

        if (__any(mt > mrow + 11.5f)) {
            const float mnew = (mt > mrow + 11.5f) ? mt : mrow;
            const float c = fast_exp2(mrow - mnew);
            lrow *= c;
            mrow = mnew;
            #pragma unroll
            for (int i = 0; i < 4; ++i) {
                const float ci = __shfl(c, lq * 4 + i);
                #pragma unroll
                for (int ni = 0; ni < 4; ++ni)
                    oacc[ni][i] *= ci;
            }
        }

        float ps = 0.f;
        #pragma unroll
        for (int ni = 0; ni < 4; ++ni)
            #pragma unroll
            for (int i = 0; i < 4; ++i) {
                const float p = fast_exp2(sc[ni][i] - mrow);
                sc[ni][i] = p;
                ps += p;
            }
        ps += __shfl_xor(ps, 16);
        ps += __shfl_xor(ps, 32);
        lrow += ps;

        #pragma unroll
        for (int ni = 0; ni < 4; ++ni) {
            const int kg0  = ni * 16 + lq * 4;
            const int slot = (kg0 >> 3) ^ (fr & 7);
            ushort4 pk;
            pk.x = f2h(sc[ni][0]); pk.y = f2h(sc[ni][1]);
            pk.z = f2h(sc[ni][2]); pk.w = f2h(sc[ni][3]);
            *(ushort4*)&Pt[w][fr * 64 + slot * 8 + (kg0 & 7)] = pk;
        }

        #pragma unroll
        for (int ks = 0; ks < 2; ++ks) {
            f16x8 pf, vf[4];
            pf = *(const f16x8*)&Pt[w][fr * 64 + (((ks * 4 + lq) ^ (fr & 7)) * 8)];
            #pragma unroll
            for (int ni = 0; ni < 4; ++ni)
                vf[ni] = *(const f16x8*)&Vt[cur][(ni * 16 + fr) * 64
                                                 + (((ks * 4 + lq) ^ (fr & 7)) * 8)];
            __builtin_amdgcn_s_setprio(1);
            #pragma unroll
            for (int ni = 0; ni < 4; ++ni)
                oacc[ni] = __builtin_amdgcn_mfma_f32_16x16x32_f16(
                    pf, vf[ni], oacc[ni], 0, 0, 0);
            __builtin_amdgcn_s_setprio(0);
        }
        cur ^= 1;
    }

    const float inv = 1.f / lrow;
    #pragma unroll
    for (int i = 0; i < 4; ++i) {
        const float invi = __shfl(inv, lq * 4 + i);
        const size_t row = qbase + lq * 4 + i;
        #pragma unroll
        for (int ni = 0; ni < 4; ++ni) {
            const float o = oacc[ni][i] * invi;
            const size_t addr = row * kD + hp * kGHD + g * kHD + ni * 16 + fr;
            oh[addr] = f2h(o);
        }
    }
}

// ---------------------------------------------------------------------------
extern "C" void kernel_launch(void* const* d_in, const int* in_sizes, int n_in,
                              void* d_out, int out_size, void* d_ws, size_t ws_size,
                              hipStream_t stream)
{
    const float* x  = (const float*)d_in[0];
    const float* Wq = (const float*)d_in[1];
    const float* bq = (const float*)d_in[2];
    const float* Wk = (const float*)d_in[3];
    const float* bk = (const float*)d_in[4];
    const float* Wv = (const float*)d_in[5];
    const float* bv = (const float*)d_in[6];
    const float* Wo = (const float*)d_in[7];
    const float* bo = (const float*)d_in[8];
    float* out = (float*)d_out;

    // workspace layout (~48 MB)
    char* p = (char*)d_ws;
    ushort* xf    = (ushort*)p; p += (size_t)kS * kD * 2;        // x f16
    ushort* wqkvf = (ushort*)p; p += (size_t)kNQKV * kD * 2;     // Wqkv f16 (Wq pre-scaled)
    ushort* wof   = (ushort*)p; p += (size_t)kD * kD * 2;        // Wo f16
    float*  bqkv  = (float*)p;  p += 16384;
    ushort* qb16  = (ushort*)p; p += (size_t)kS * kD * 2;
    ushort* kb16  = (ushort*)p; p += (size_t)kS * kGHD * 2;
    ushort* vt16  = (ushort*)p; p += (size_t)kGHD * kS * 2;
    ushort* aoh   = (ushort*)p;                                  // attn out f16

    cvt_f16<<<kS * kD / 1024, 256, 0, stream>>>(x, xf, kS * kD, 1.f);
    cvt_f16<<<kD * kD / 1024, 256, 0, stream>>>(Wq, wqkvf, kD * kD, kQScale);
    cvt_f16<<<kGHD * kD / 1024, 256, 0, stream>>>(Wk, wqkvf + (size_t)kD * kD, kGHD * kD, 1.f);
    cvt_f16<<<kGHD * kD / 1024, 256, 0, stream>>>(
        Wv, wqkvf + (size_t)(kD + kGHD) * kD, kGHD * kD, 1.f);
    cvt_f16<<<kD * kD / 1024, 256, 0, stream>>>(Wo, wof, kD * kD, 1.f);
    prep_bias<<<(kNQKV + 255) / 256, 256, 0, stream>>>(bq, bk, bv, bqkv);

    // fused QKV projection (8-wave, prefetch) -> q(prescaled),k row-major; v^T
    gemm_qkv<<<(kNQKV / 128) * (kS / 128), 512, 0, stream>>>(
        xf, wqkvf, bqkv, qb16, kb16, vt16, kD, kNQKV / 128);

    // MFMA flash attention (swapped QK^T, in-lane softmax, defer-max)
    gqa_attn_mfma<<<dim3(kS / 32, kG), 512, 0, stream>>>(qb16, kb16, vt16, aoh);

    // output projection (single-f16 A, 8-wave, prefetch)
    gemm_o<<<(kD / 128) * (kS / 128), 512, 0, stream>>>(
        aoh, wof, bo, out, kD, kD, kD / 128);
}